// Round 2
// baseline (234.132 us; speedup 1.0000x reference)
//
#include <hip/hip_runtime.h>
#include <hip/hip_bf16.h>
#include <hip/hip_fp16.h>

#define L_SEQ 2048
#define D_MODEL 512
#define NH 8
#define HD 64
#define EPSF 1e-5f

// u f16 layout: [512 ch][2560], logical s at col 256+s; margins zeroed.
#define UPAD 2560
#define UOFF 256
// filter LDS: 8 phase copies, stride 2120 f16 (=1060 words, == 4 mod 32 -> 2-way-free banks)
#define XLEN 2112
#define XPAD 2120

typedef __attribute__((ext_vector_type(8))) short short8;
typedef __attribute__((ext_vector_type(8))) _Float16 half8;
typedef __attribute__((ext_vector_type(4))) _Float16 half4v;
typedef __attribute__((ext_vector_type(4))) float f32x4;

// load 8 consecutive fp32 and convert to bf16 short8 (same __float2bfloat16 as old prep)
__device__ inline short8 cvt8(const float* __restrict__ p) {
  float4 f0 = *(const float4*)p;
  float4 f1 = *(const float4*)(p + 4);
  short8 r;
  union { __hip_bfloat16 h; short s; } u;
  u.h = __float2bfloat16(f0.x); r[0] = u.s;
  u.h = __float2bfloat16(f0.y); r[1] = u.s;
  u.h = __float2bfloat16(f0.z); r[2] = u.s;
  u.h = __float2bfloat16(f0.w); r[3] = u.s;
  u.h = __float2bfloat16(f1.x); r[4] = u.s;
  u.h = __float2bfloat16(f1.y); r[5] = u.s;
  u.h = __float2bfloat16(f1.z); r[6] = u.s;
  u.h = __float2bfloat16(f1.w); r[7] = u.s;
  return r;
}

// ---------------- batched GEMM: q,k,v,filters from fp32 inputs (in-register bf16 cvt);
// l2norm + f16 pad-write for k,v; margin zeroing folded in ----------------
__global__ __launch_bounds__(256) void gemm4_kernel(
    const float* __restrict__ x, const float* __restrict__ sb,
    const float* __restrict__ wq, const float* __restrict__ wk,
    const float* __restrict__ wv, const float* __restrict__ td,
    const float* __restrict__ bq, const float* __restrict__ bk,
    const float* __restrict__ bv, const float* __restrict__ btd,
    float* __restrict__ qout, float* __restrict__ fT,
    _Float16* __restrict__ ku16, _Float16* __restrict__ vu16)
{
  int z = blockIdx.z;
  const float* A = (z == 3) ? sb : x;
  const float* W = (z == 0) ? wq : (z == 1) ? wk : (z == 2) ? wv : td;
  const float* bias = (z == 0) ? bq : (z == 1) ? bk : (z == 2) ? bv : btd;
  const int M = L_SEQ, K = D_MODEL;
  const int N = D_MODEL;
  int lane = threadIdx.x & 63;
  int wave = threadIdx.x >> 6;
  int m0 = blockIdx.x * 64 + wave * 16;
  int n0 = blockIdx.y * 64;
  int lrow = lane & 15, quad = lane >> 4;

  // margin zeroing for the f16 padded arrays (replaces prep_kernel's zero pass);
  // disjoint from all interior writes, consumed only by the NEXT kernel (conv).
  if ((z == 1 || z == 2) && (blockIdx.x == 0 || blockIdx.x == 31)) {
    _Float16* u16m = (z == 1) ? ku16 : vu16;
    int colbase = (blockIdx.x == 0) ? 0 : 2304;
#pragma unroll
    for (int t = 0; t < 8; ++t) {
      int idx = threadIdx.x + t * 256;      // 0..2047
      int row = idx >> 5, cc = idx & 31;    // 64 rows x 32 chunks of 8 f16
      *(int4*)(u16m + (size_t)(n0 + row) * UPAD + colbase + cc * 8) = int4{0, 0, 0, 0};
    }
  }

  const float* Ap = A + (size_t)(m0 + lrow) * K + quad * 8;
  const float* Wp = W + (size_t)(n0 + lrow) * K + quad * 8;
  f32x4 acc[4] = {};
  for (int k0 = 0; k0 < K; k0 += 32) {
    short8 a = cvt8(Ap + k0);
#pragma unroll
    for (int j = 0; j < 4; ++j) {
      short8 b = cvt8(Wp + k0 + (size_t)j * 16 * K);
      acc[j] = __builtin_amdgcn_mfma_f32_16x16x32_bf16(a, b, acc[j], 0, 0, 0);
    }
  }
  float bw[4];
#pragma unroll
  for (int j = 0; j < 4; ++j) bw[j] = bias[n0 + j * 16 + lrow];
  if (z == 0) {
#pragma unroll
    for (int j = 0; j < 4; ++j)
#pragma unroll
      for (int r = 0; r < 4; ++r)
        qout[(size_t)(m0 + quad * 4 + r) * N + n0 + j * 16 + lrow] = acc[j][r] + bw[j];
  } else if (z == 3) {
#pragma unroll
    for (int j = 0; j < 4; ++j) {
      float4 ov = {acc[j][0] + bw[j], acc[j][1] + bw[j], acc[j][2] + bw[j], acc[j][3] + bw[j]};
      *(float4*)(fT + (size_t)(n0 + j * 16 + lrow) * M + m0 + quad * 4) = ov;
    }
  } else {
    float val[4][4];
#pragma unroll
    for (int j = 0; j < 4; ++j)
#pragma unroll
      for (int r = 0; r < 4; ++r) val[j][r] = acc[j][r] + bw[j];
    // l2-normalize over head dim (this block's 64 n-cols = one head)
    float pr[4];
#pragma unroll
    for (int r = 0; r < 4; ++r)
      pr[r] = val[0][r] * val[0][r] + val[1][r] * val[1][r] +
              val[2][r] * val[2][r] + val[3][r] * val[3][r];
#pragma unroll
    for (int off = 1; off < 16; off <<= 1)
#pragma unroll
      for (int r = 0; r < 4; ++r)
        pr[r] += __shfl_xor(pr[r], off, 64);
    _Float16* u16 = (z == 1) ? ku16 : vu16;
#pragma unroll
    for (int r = 0; r < 4; ++r) {
      float inv = 1.f / fmaxf(sqrtf(pr[r]), EPSF);
#pragma unroll
      for (int j = 0; j < 4; ++j) val[j][r] *= inv;
    }
#pragma unroll
    for (int j = 0; j < 4; ++j) {
      half4v pk = {(_Float16)val[j][0], (_Float16)val[j][1],
                   (_Float16)val[j][2], (_Float16)val[j][3]};
      *(half4v*)(u16 + (size_t)(n0 + j * 16 + lrow) * UPAD + UOFF + m0 + quad * 4) = pk;
    }
  }
}

// ---------------- causal conv via MFMA Toeplitz, filter in LDS (f16) ----------------
// block = 1 channel, 4 waves; wave = tile-pair {l0, 1792-l0}, BOTH tensors.
// A[m][k] = F[d+m-k] (d = l0+256-32i) read from 8-phase reversed LDS copies (b128);
// B[k][n] = u[s0+k+16n] f16 contiguous 16B/lane global. 4 MFMAs/step (k,v x hi,lo tile).
__global__ __launch_bounds__(256) void conv_kernel(
    const _Float16* __restrict__ ku16, const _Float16* __restrict__ vu16,
    const float* __restrict__ fT, float* __restrict__ oK, float* __restrict__ oV)
{
  __shared__ _Float16 lds_f[8 * XPAD];
  int c = blockIdx.x;
  int tid = threadIdx.x;
  const float* Fc = fT + (size_t)c * L_SEQ;
  // stage: lds_f[p][x] = f16(F[2063 - x - p]), zero outside [0,2048)
#pragma unroll
  for (int p = 0; p < 8; ++p) {
#pragma unroll
    for (int t = 0; t < 9; ++t) {
      int xx = tid + t * 256;
      if (xx < XLEN) {
        int j = 2063 - xx - p;
        float v = (j >= 0 && j < L_SEQ) ? Fc[j] : 0.f;
        lds_f[p * XPAD + xx] = (_Float16)v;
      }
    }
  }
  __syncthreads();

  int wave = tid >> 6, lane = tid & 63;
  int pair = wave;
  int l0_lo = 256 * pair;
  int l0_hi = 1792 - l0_lo;
  int mn = lane & 15, quad = lane >> 4;

  const _Float16* puk = ku16 + (size_t)c * UPAD + 16 * mn + 8 * quad;
  const _Float16* puv = vu16 + (size_t)c * UPAD + 16 * mn + 8 * quad;

  int j0c = 2063 - mn;
  int p8 = j0c & 7;
  int xb0 = (j0c - p8) + 8 * quad;
  const _Float16* pf_hi = lds_f + p8 * XPAD + (xb0 - (l0_hi + 256));
  const _Float16* pf_lo = lds_f + p8 * XPAD + (xb0 - (l0_lo + 256));

  int steps_lo = pair * 8 + 9;
  int steps_hi = 65 - pair * 8;
  f32x4 ak_hi = {}, ak_lo = {}, av_hi = {}, av_lo = {};
#pragma unroll 2
  for (int i = 0; i < steps_lo; ++i) {
    half8 bk = *(const half8*)puk;
    half8 bv = *(const half8*)puv;
    half8 fh = *(const half8*)pf_hi;
    half8 fl = *(const half8*)pf_lo;
    puk += 32; puv += 32; pf_hi += 32; pf_lo += 32;
    ak_hi = __builtin_amdgcn_mfma_f32_16x16x32_f16(fh, bk, ak_hi, 0, 0, 0);
    av_hi = __builtin_amdgcn_mfma_f32_16x16x32_f16(fh, bv, av_hi, 0, 0, 0);
    ak_lo = __builtin_amdgcn_mfma_f32_16x16x32_f16(fl, bk, ak_lo, 0, 0, 0);
    av_lo = __builtin_amdgcn_mfma_f32_16x16x32_f16(fl, bv, av_lo, 0, 0, 0);
  }
#pragma unroll 2
  for (int i = steps_lo; i < steps_hi; ++i) {
    half8 bk = *(const half8*)puk;
    half8 bv = *(const half8*)puv;
    half8 fh = *(const half8*)pf_hi;
    puk += 32; puv += 32; pf_hi += 32;
    ak_hi = __builtin_amdgcn_mfma_f32_16x16x32_f16(fh, bk, ak_hi, 0, 0, 0);
    av_hi = __builtin_amdgcn_mfma_f32_16x16x32_f16(fh, bv, av_hi, 0, 0, 0);
  }
  size_t ob = (size_t)c * L_SEQ + 16 * mn + 4 * quad;
  *(float4*)(oK + ob + l0_hi) = float4{ak_hi[0], ak_hi[1], ak_hi[2], ak_hi[3]};
  *(float4*)(oK + ob + l0_lo) = float4{ak_lo[0], ak_lo[1], ak_lo[2], ak_lo[3]};
  *(float4*)(oV + ob + l0_hi) = float4{av_hi[0], av_hi[1], av_hi[2], av_hi[3]};
  *(float4*)(oV + ob + l0_lo) = float4{av_lo[0], av_lo[1], av_lo[2], av_lo[3]};
}

// ---------------- fused gate + partials per (h, chunk) ----------------
__global__ __launch_bounds__(256) void gatepart_kernel(const float* __restrict__ kf,
    const float* __restrict__ vf, const float* __restrict__ wgz_w,
    const float* __restrict__ wgz_b, const float* __restrict__ kvs,
    float* __restrict__ g, float* __restrict__ A, float* __restrict__ gsum)
{
  __shared__ float MT[64][68];
  __shared__ float kb[64][68];
  __shared__ float kbT[64][68];  // kbT[t][d] transposed copy: A-accum reads become b128, conflict-free
  __shared__ float vb[64][68];
  __shared__ float yb[64][68];
  __shared__ float part[4][64];
  __shared__ float gl[64];
  int h = blockIdx.y, ch = blockIdx.x;
  int t0 = ch * 64, tid = threadIdx.x;
#pragma unroll
  for (int k = 0; k < 16; ++k) {
    int idx = tid + k * 256;
    int a = idx >> 6, b = idx & 63;
    MT[b][a] = wgz_w[idx] * kvs[idx];
    float kv = kf[(size_t)(h * 64 + a) * L_SEQ + t0 + b];
    kb[a][b] = kv;
    kbT[b][a] = kv;
    vb[a][b] = vf[(size_t)(h * 64 + a) * L_SEQ + t0 + b];
  }
  __syncthreads();
  int lg = tid & 15, dg = tid >> 4;
  {
    float acc[4][4] = {};
    for (int e = 0; e < 64; ++e) {
      float4 mv4 = *(const float4*)(&MT[e][dg * 4]);
      float4 kv4 = *(const float4*)(&kb[e][lg * 4]);
      float mvv[4] = {mv4.x, mv4.y, mv4.z, mv4.w};
      float kvv[4] = {kv4.x, kv4.y, kv4.z, kv4.w};
#pragma unroll
      for (int r = 0; r < 4; ++r)
#pragma unroll
        for (int j = 0; j < 4; ++j)
          acc[r][j] = fmaf(mvv[r], kvv[j], acc[r][j]);
    }
#pragma unroll
    for (int r = 0; r < 4; ++r)
#pragma unroll
      for (int j = 0; j < 4; ++j)
        yb[dg * 4 + r][lg * 4 + j] = acc[r][j];
  }
  __syncthreads();
  {
    int l = tid & 63, p = tid >> 6;
    float s = 0.f;
#pragma unroll
    for (int dd = 0; dd < 16; ++dd)
      s = fmaf(yb[p * 16 + dd][l], vb[p * 16 + dd][l], s);
    part[p][l] = s;
  }
  __syncthreads();
  if (tid < 64) {
    float logit = part[0][tid] + part[1][tid] + part[2][tid] + part[3][tid] + wgz_b[0];
    float rl = fmaxf(logit, 0.f);
    float gv = rl * rl + EPSF;
    g[h * L_SEQ + t0 + tid] = gv;
    gl[tid] = gv;
  }
  __syncthreads();
  // parallel gsum reduce (wave 0)
  if (tid < 64) {
    float s = gl[tid];
#pragma unroll
    for (int off = 1; off < 64; off <<= 1) s += __shfl_xor(s, off, 64);
    if (tid == 0) gsum[h * 32 + ch] = s;
  }
  int eg = tid & 15, dg2 = tid >> 4;
  float acc[4][4] = {};
  for (int t = 0; t < 64; ++t) {
    float gt = gl[t];
    float4 k4 = *(const float4*)(&kbT[t][eg * 4]);
    float kv4[4] = {k4.x * gt, k4.y * gt, k4.z * gt, k4.w * gt};
    float vv4[4];
#pragma unroll
    for (int r = 0; r < 4; ++r) vv4[r] = vb[dg2 * 4 + r][t];
#pragma unroll
    for (int r = 0; r < 4; ++r)
#pragma unroll
      for (int j = 0; j < 4; ++j)
        acc[r][j] = fmaf(vv4[r], kv4[j], acc[r][j]);
  }
  float* Ap = A + ((size_t)(h * 32 + ch)) * 4096;
#pragma unroll
  for (int r = 0; r < 4; ++r)
#pragma unroll
    for (int j = 0; j < 4; ++j)
      Ap[(dg2 * 4 + r) * 64 + eg * 4 + j] = acc[r][j];
}

// ---------------- attention: inline chunk-prefix (reads raw A, gsum) + in-chunk gated
// quadratic, /G, l2norm, bf16 store.  prefix_kernel is FUSED here: block (h,ch) sums
// A[h, c<ch] in ascending c (same rounding order as the old serial prefix). ----------------
__global__ __launch_bounds__(256) void attn_kernel(const float* __restrict__ q,
    const float* __restrict__ kf, const float* __restrict__ vf, const float* __restrict__ g,
    const float* __restrict__ A, const float* __restrict__ gsum,
    __hip_bfloat16* __restrict__ sp)
{
  __shared__ float qT[64][68];
  __shared__ float SW[64][69];
  __shared__ float vb[64][68];
  __shared__ float kb[64][69];
  __shared__ float gl[64], Gs[64], rsq[64];
  int h = blockIdx.y, ch = blockIdx.x;
  int t0 = ch * 64, tid = threadIdx.x;
#pragma unroll
  for (int k = 0; k < 16; ++k) {
    int idx = tid + k * 256;
    int a = idx >> 6, b = idx & 63;
    qT[b][a] = q[(size_t)(t0 + a) * D_MODEL + h * 64 + b];
    vb[a][b] = vf[(size_t)(h * 64 + a) * L_SEQ + t0 + b];
    kb[a][b] = kf[(size_t)(h * 64 + a) * L_SEQ + t0 + b];
  }
  // Sprev = sum over previous chunks' raw states (was the prefix kernel)
  {
    float4 sacc[4] = {};
    const float* Abase = A + ((size_t)(h * 32)) * 4096 + tid * 16;
    for (int c = 0; c < ch; ++c) {
      const float* Ac = Abase + (size_t)c * 4096;
#pragma unroll
      for (int t = 0; t < 4; ++t) {
        float4 v = *(const float4*)(Ac + t * 4);
        sacc[t].x += v.x; sacc[t].y += v.y; sacc[t].z += v.z; sacc[t].w += v.w;
      }
    }
    int a0 = tid >> 2, b0 = (tid & 3) * 16;
#pragma unroll
    for (int t = 0; t < 4; ++t) {
      SW[a0][b0 + t * 4 + 0] = sacc[t].x;
      SW[a0][b0 + t * 4 + 1] = sacc[t].y;
      SW[a0][b0 + t * 4 + 2] = sacc[t].z;
      SW[a0][b0 + t * 4 + 3] = sacc[t].w;
    }
  }
  if (tid < 64) { gl[tid] = g[h * L_SEQ + t0 + tid]; rsq[tid] = 0.f; }
  __syncthreads();
  if (tid < 64) {
    // Gprev = sum of previous chunks' gate sums (was prefix over gsum)
    float gp = (tid < ch) ? gsum[h * 32 + tid] : 0.f;
#pragma unroll
    for (int off = 1; off < 64; off <<= 1) gp += __shfl_xor(gp, off, 64);
    float val = gl[tid];
#pragma unroll
    for (int off = 1; off < 64; off <<= 1) {
      float o = __shfl_up(val, (unsigned)off, 64);
      if (tid >= off) val += o;
    }
    Gs[tid] = fmaxf(gp + val, EPSF);
  }
  int lg = tid & 15, eg = tid >> 4;
  // merged loop: q@Sprev (acc) and q@v (sc) share the qT loads
  float acc[4][4] = {};
  float sc[4][4] = {};
  for (int d = 0; d < 64; ++d) {
    float4 q4 = *(const float4*)(&qT[d][lg * 4]);
    float qv[4] = {q4.x, q4.y, q4.z, q4.w};
    float sv[4];
#pragma unroll
    for (int j = 0; j < 4; ++j) sv[j] = SW[d][eg * 4 + j];
    float4 v4 = *(const float4*)(&vb[d][eg * 4]);
    float vv[4] = {v4.x, v4.y, v4.z, v4.w};
#pragma unroll
    for (int r = 0; r < 4; ++r)
#pragma unroll
      for (int j = 0; j < 4; ++j) {
        acc[r][j] = fmaf(qv[r], sv[j], acc[r][j]);
        sc[r][j] = fmaf(qv[r], vv[j], sc[r][j]);
      }
  }
  __syncthreads();
#pragma unroll
  for (int r = 0; r < 4; ++r)
#pragma unroll
    for (int m = 0; m < 4; ++m) {
      int ll = lg * 4 + r, tt = eg * 4 + m;
      SW[ll][tt] = (tt <= ll) ? sc[r][m] * gl[tt] : 0.f;
    }
  __syncthreads();
  for (int t = 0; t < 64; ++t) {
    float wv4[4], kv4[4];
#pragma unroll
    for (int r = 0; r < 4; ++r) wv4[r] = SW[lg * 4 + r][t];
#pragma unroll
    for (int j = 0; j < 4; ++j) kv4[j] = kb[eg * 4 + j][t];
#pragma unroll
    for (int r = 0; r < 4; ++r)
#pragma unroll
      for (int j = 0; j < 4; ++j)
        acc[r][j] = fmaf(wv4[r], kv4[j], acc[r][j]);
  }
  float val[4][4];
  int egw = (tid >> 4) & 3;
#pragma unroll
  for (int r = 0; r < 4; ++r) {
    float gi = 1.f / Gs[lg * 4 + r];
    float pr = 0.f;
#pragma unroll
    for (int j = 0; j < 4; ++j) { float v = acc[r][j] * gi; val[r][j] = v; pr = fmaf(v, v, pr); }
    pr += __shfl_xor(pr, 16, 64);
    pr += __shfl_xor(pr, 32, 64);
    if (egw == 0) atomicAdd(&rsq[lg * 4 + r], pr);
  }
  __syncthreads();
#pragma unroll
  for (int r = 0; r < 4; ++r) {
    float inv = 1.f / fmaxf(sqrtf(rsq[lg * 4 + r]), EPSF);
    union { ushort4 u; __hip_bfloat16 hh[4]; } pk;
#pragma unroll
    for (int j = 0; j < 4; ++j) pk.hh[j] = __float2bfloat16(val[r][j] * inv);
    *(ushort4*)(sp + (size_t)(t0 + lg * 4 + r) * D_MODEL + h * 64 + eg * 4) = pk.u;
  }
}

// ---------------- final GEMM: out = sp @ wo^T + b (wo fp32, in-register cvt) ----------------
__global__ __launch_bounds__(256) void gemm_out_kernel(const __hip_bfloat16* __restrict__ A,
    const float* __restrict__ W, const float* __restrict__ bias,
    float* __restrict__ O)
{
  const int N = D_MODEL, K = D_MODEL;
  int lane = threadIdx.x & 63;
  int wave = threadIdx.x >> 6;
  int m0 = blockIdx.x * 64 + wave * 16;
  int n0 = blockIdx.y * 64;
  int lrow = lane & 15, quad = lane >> 4;
  const __hip_bfloat16* Ap = A + (size_t)(m0 + lrow) * K + quad * 8;
  const float* Wp = W + (size_t)(n0 + lrow) * K + quad * 8;
  f32x4 acc[4] = {};
  for (int k0 = 0; k0 < K; k0 += 32) {
    short8 a = *(const short8*)(Ap + k0);
#pragma unroll
    for (int j = 0; j < 4; ++j) {
      short8 b = cvt8(Wp + k0 + (size_t)j * 16 * K);
      acc[j] = __builtin_amdgcn_mfma_f32_16x16x32_bf16(a, b, acc[j], 0, 0, 0);
    }
  }
#pragma unroll
  for (int j = 0; j < 4; ++j) {
    int n = n0 + j * 16 + lrow;
    float bv = bias[n];
#pragma unroll
    for (int r = 0; r < 4; ++r)
      O[(size_t)(m0 + quad * 4 + r) * N + n] = acc[j][r] + bv;
  }
}

extern "C" void kernel_launch(void* const* d_in, const int* in_sizes, int n_in,
                              void* d_out, int out_size, void* d_ws, size_t ws_size,
                              hipStream_t stream) {
  const float* x = (const float*)d_in[0];
  const float* sb = (const float*)d_in[1];
  const float* wq_w = (const float*)d_in[2];
  const float* wq_b = (const float*)d_in[3];
  const float* wk_w = (const float*)d_in[4];
  const float* wk_b = (const float*)d_in[5];
  const float* wv_w = (const float*)d_in[6];
  const float* wv_b = (const float*)d_in[7];
  const float* wo_w = (const float*)d_in[8];
  const float* wo_b = (const float*)d_in[9];
  const float* td_w = (const float*)d_in[10];
  const float* td_b = (const float*)d_in[11];
  const float* wgz_w = (const float*)d_in[12];
  const float* wgz_b = (const float*)d_in[13];
  const float* kvs = (const float*)d_in[14];
  float* out = (float*)d_out;

  char* ws = (char*)d_ws;
  size_t off = 0;
  auto alloc = [&](size_t bytes) -> void* {
    void* p = ws + off;
    off += (bytes + 255) & ~(size_t)255;
    return p;
  };
  __hip_bfloat16* spb = (__hip_bfloat16*)alloc((size_t)L_SEQ * D_MODEL * 2);
  _Float16* ku16 = (_Float16*)alloc((size_t)D_MODEL * UPAD * 2);
  _Float16* vu16 = (_Float16*)alloc((size_t)D_MODEL * UPAD * 2);
  float* qbuf  = (float*)alloc((size_t)L_SEQ * D_MODEL * 4);
  float* fT    = (float*)alloc((size_t)D_MODEL * L_SEQ * 4);
  float* kfT   = (float*)alloc((size_t)D_MODEL * L_SEQ * 4);
  float* vfT   = (float*)alloc((size_t)D_MODEL * L_SEQ * 4);
  float* gbuf  = (float*)alloc((size_t)NH * L_SEQ * 4);
  float* gsum  = (float*)alloc((size_t)NH * 32 * 4);
  float* Abuf  = (float*)alloc((size_t)NH * 32 * 4096 * 4);

  gemm4_kernel<<<dim3(L_SEQ / 64, D_MODEL / 64, 4), 256, 0, stream>>>(
      x, sb, wq_w, wk_w, wv_w, td_w, wq_b, wk_b, wv_b, td_b, qbuf, fT,
      ku16, vu16);
  conv_kernel<<<512, 256, 0, stream>>>(ku16, vu16, fT, kfT, vfT);
  gatepart_kernel<<<dim3(32, 8), 256, 0, stream>>>(kfT, vfT, wgz_w, wgz_b, kvs, gbuf, Abuf, gsum);
  attn_kernel<<<dim3(32, 8), 256, 0, stream>>>(qbuf, kfT, vfT, gbuf, Abuf, gsum, spb);
  gemm_out_kernel<<<dim3(L_SEQ / 64, D_MODEL / 64), 256, 0, stream>>>(spb, wo_w, wo_b, out);
}

// Round 3
// 200.530 us; speedup vs baseline: 1.1676x; 1.1676x over previous
//
#include <hip/hip_runtime.h>
#include <hip/hip_bf16.h>
#include <hip/hip_fp16.h>

#define L_SEQ 2048
#define D_MODEL 512
#define NH 8
#define HD 64
#define EPSF 1e-5f

// u f16 layout: [512 ch][2560], logical s at col 256+s; margins zeroed.
#define UPAD 2560
#define UOFF 256
// filter LDS: 8 phase copies, stride 2120 f16 (=1060 words, == 4 mod 32 -> 2-way-free banks)
#define XLEN 2112
#define XPAD 2120

typedef __attribute__((ext_vector_type(8))) short short8;
typedef __attribute__((ext_vector_type(8))) _Float16 half8;
typedef __attribute__((ext_vector_type(4))) _Float16 half4v;
typedef __attribute__((ext_vector_type(4))) float f32x4;

// ---------------- prep: fp32->bf16 for 7 tensors + zero u16 margins ----------------
__global__ __launch_bounds__(256) void prep_kernel(const float* __restrict__ x,
    const float* __restrict__ sb, const float* __restrict__ wq, const float* __restrict__ wk,
    const float* __restrict__ wv, const float* __restrict__ td, const float* __restrict__ wo,
    __hip_bfloat16* __restrict__ xb, __hip_bfloat16* __restrict__ sbb,
    __hip_bfloat16* __restrict__ wqb, __hip_bfloat16* __restrict__ wkb,
    __hip_bfloat16* __restrict__ wvb, __hip_bfloat16* __restrict__ tdb,
    __hip_bfloat16* __restrict__ wob,
    _Float16* __restrict__ ku16, _Float16* __restrict__ vu16)
{
  int i = blockIdx.x * 256 + threadIdx.x;
  if (i < 2097152) {
    if (i < 1048576) xb[i] = __float2bfloat16(x[i]);
    else sbb[i - 1048576] = __float2bfloat16(sb[i - 1048576]);
  } else if (i < 3407872) {
    int j = i - 2097152;
    int w = j >> 18;
    int r = j & 262143;
    const float* s = (w == 0) ? wq : (w == 1) ? wk : (w == 2) ? wv : (w == 3) ? td : wo;
    __hip_bfloat16* d = (w == 0) ? wqb : (w == 1) ? wkb : (w == 2) ? wvb : (w == 3) ? tdb : wob;
    d[r] = __float2bfloat16(s[r]);
  } else if (i < 3473408) {
    // zero u16 margins: 2 arrays x 512 rows x 64 chunks of 8 f16 (16B)
    int t = i - 3407872;
    int arr = t >> 15;
    int rem = t & 32767;
    int row = rem >> 6;
    int cc = rem & 63;
    int col = (cc < 32) ? cc * 8 : 2304 + (cc - 32) * 8;
    _Float16* base = arr ? vu16 : ku16;
    *(int4*)(base + (size_t)row * UPAD + col) = int4{0, 0, 0, 0};
  }
}

// ---------------- batched GEMM: q,k,v,filters; l2norm + f16 pad-write for k,v ----------------
__global__ __launch_bounds__(256) void gemm4_kernel(
    const __hip_bfloat16* __restrict__ xb, const __hip_bfloat16* __restrict__ sbb,
    const __hip_bfloat16* __restrict__ wqb, const __hip_bfloat16* __restrict__ wkb,
    const __hip_bfloat16* __restrict__ wvb, const __hip_bfloat16* __restrict__ tdb,
    const float* __restrict__ bq, const float* __restrict__ bk,
    const float* __restrict__ bv, const float* __restrict__ btd,
    float* __restrict__ qout, float* __restrict__ fT,
    _Float16* __restrict__ ku16, _Float16* __restrict__ vu16)
{
  int z = blockIdx.z;
  const __hip_bfloat16* A = (z == 3) ? sbb : xb;
  const __hip_bfloat16* W = (z == 0) ? wqb : (z == 1) ? wkb : (z == 2) ? wvb : tdb;
  const float* bias = (z == 0) ? bq : (z == 1) ? bk : (z == 2) ? bv : btd;
  const int M = L_SEQ, N = D_MODEL, K = D_MODEL;
  int lane = threadIdx.x & 63;
  int wave = threadIdx.x >> 6;
  int m0 = blockIdx.x * 64 + wave * 16;
  int n0 = blockIdx.y * 64;
  int lrow = lane & 15, quad = lane >> 4;
  const __hip_bfloat16* Ap = A + (size_t)(m0 + lrow) * K + quad * 8;
  const __hip_bfloat16* Wp = W + (size_t)(n0 + lrow) * K + quad * 8;
  f32x4 acc[4] = {};
  for (int k0 = 0; k0 < K; k0 += 32) {
    short8 a = *(const short8*)(Ap + k0);
#pragma unroll
    for (int j = 0; j < 4; ++j) {
      short8 b = *(const short8*)(Wp + k0 + (size_t)j * 16 * K);
      acc[j] = __builtin_amdgcn_mfma_f32_16x16x32_bf16(a, b, acc[j], 0, 0, 0);
    }
  }
  float bw[4];
#pragma unroll
  for (int j = 0; j < 4; ++j) bw[j] = bias[n0 + j * 16 + lrow];
  if (z == 0) {
#pragma unroll
    for (int j = 0; j < 4; ++j)
#pragma unroll
      for (int r = 0; r < 4; ++r)
        qout[(size_t)(m0 + quad * 4 + r) * N + n0 + j * 16 + lrow] = acc[j][r] + bw[j];
  } else if (z == 3) {
#pragma unroll
    for (int j = 0; j < 4; ++j) {
      float4 ov = {acc[j][0] + bw[j], acc[j][1] + bw[j], acc[j][2] + bw[j], acc[j][3] + bw[j]};
      *(float4*)(fT + (size_t)(n0 + j * 16 + lrow) * M + m0 + quad * 4) = ov;
    }
  } else {
    float val[4][4];
#pragma unroll
    for (int j = 0; j < 4; ++j)
#pragma unroll
      for (int r = 0; r < 4; ++r) val[j][r] = acc[j][r] + bw[j];
    // l2-normalize over head dim (this block's 64 n-cols = one head)
    float pr[4];
#pragma unroll
    for (int r = 0; r < 4; ++r)
      pr[r] = val[0][r] * val[0][r] + val[1][r] * val[1][r] +
              val[2][r] * val[2][r] + val[3][r] * val[3][r];
#pragma unroll
    for (int off = 1; off < 16; off <<= 1)
#pragma unroll
      for (int r = 0; r < 4; ++r)
        pr[r] += __shfl_xor(pr[r], off, 64);
    _Float16* u16 = (z == 1) ? ku16 : vu16;
#pragma unroll
    for (int r = 0; r < 4; ++r) {
      float inv = 1.f / fmaxf(sqrtf(pr[r]), EPSF);
#pragma unroll
      for (int j = 0; j < 4; ++j) val[j][r] *= inv;
    }
#pragma unroll
    for (int j = 0; j < 4; ++j) {
      half4v pk = {(_Float16)val[j][0], (_Float16)val[j][1],
                   (_Float16)val[j][2], (_Float16)val[j][3]};
      *(half4v*)(u16 + (size_t)(n0 + j * 16 + lrow) * UPAD + UOFF + m0 + quad * 4) = pk;
    }
  }
}

// ---------------- causal conv via MFMA Toeplitz, filter in LDS (f16) ----------------
// block = 1 channel, 4 waves; wave = tile-pair {l0, 1792-l0}, BOTH tensors.
// A[m][k] = F[d+m-k] (d = l0+256-32i) read from 8-phase reversed LDS copies (b128);
// B[k][n] = u[s0+k+16n] f16 contiguous 16B/lane global. 4 MFMAs/step (k,v x hi,lo tile).
__global__ __launch_bounds__(256) void conv_kernel(
    const _Float16* __restrict__ ku16, const _Float16* __restrict__ vu16,
    const float* __restrict__ fT, float* __restrict__ oK, float* __restrict__ oV)
{
  __shared__ _Float16 lds_f[8 * XPAD];
  int c = blockIdx.x;
  int tid = threadIdx.x;
  const float* Fc = fT + (size_t)c * L_SEQ;
  // stage: lds_f[p][x] = f16(F[2063 - x - p]), zero outside [0,2048)
#pragma unroll
  for (int p = 0; p < 8; ++p) {
#pragma unroll
    for (int t = 0; t < 9; ++t) {
      int xx = tid + t * 256;
      if (xx < XLEN) {
        int j = 2063 - xx - p;
        float v = (j >= 0 && j < L_SEQ) ? Fc[j] : 0.f;
        lds_f[p * XPAD + xx] = (_Float16)v;
      }
    }
  }
  __syncthreads();

  int wave = tid >> 6, lane = tid & 63;
  int pair = wave;
  int l0_lo = 256 * pair;
  int l0_hi = 1792 - l0_lo;
  int mn = lane & 15, quad = lane >> 4;

  const _Float16* puk = ku16 + (size_t)c * UPAD + 16 * mn + 8 * quad;
  const _Float16* puv = vu16 + (size_t)c * UPAD + 16 * mn + 8 * quad;

  int j0c = 2063 - mn;
  int p8 = j0c & 7;
  int xb0 = (j0c - p8) + 8 * quad;
  const _Float16* pf_hi = lds_f + p8 * XPAD + (xb0 - (l0_hi + 256));
  const _Float16* pf_lo = lds_f + p8 * XPAD + (xb0 - (l0_lo + 256));

  int steps_lo = pair * 8 + 9;
  int steps_hi = 65 - pair * 8;
  f32x4 ak_hi = {}, ak_lo = {}, av_hi = {}, av_lo = {};
#pragma unroll 2
  for (int i = 0; i < steps_lo; ++i) {
    half8 bk = *(const half8*)puk;
    half8 bv = *(const half8*)puv;
    half8 fh = *(const half8*)pf_hi;
    half8 fl = *(const half8*)pf_lo;
    puk += 32; puv += 32; pf_hi += 32; pf_lo += 32;
    ak_hi = __builtin_amdgcn_mfma_f32_16x16x32_f16(fh, bk, ak_hi, 0, 0, 0);
    av_hi = __builtin_amdgcn_mfma_f32_16x16x32_f16(fh, bv, av_hi, 0, 0, 0);
    ak_lo = __builtin_amdgcn_mfma_f32_16x16x32_f16(fl, bk, ak_lo, 0, 0, 0);
    av_lo = __builtin_amdgcn_mfma_f32_16x16x32_f16(fl, bv, av_lo, 0, 0, 0);
  }
#pragma unroll 2
  for (int i = steps_lo; i < steps_hi; ++i) {
    half8 bk = *(const half8*)puk;
    half8 bv = *(const half8*)puv;
    half8 fh = *(const half8*)pf_hi;
    puk += 32; puv += 32; pf_hi += 32;
    ak_hi = __builtin_amdgcn_mfma_f32_16x16x32_f16(fh, bk, ak_hi, 0, 0, 0);
    av_hi = __builtin_amdgcn_mfma_f32_16x16x32_f16(fh, bv, av_hi, 0, 0, 0);
  }
  size_t ob = (size_t)c * L_SEQ + 16 * mn + 4 * quad;
  *(float4*)(oK + ob + l0_hi) = float4{ak_hi[0], ak_hi[1], ak_hi[2], ak_hi[3]};
  *(float4*)(oK + ob + l0_lo) = float4{ak_lo[0], ak_lo[1], ak_lo[2], ak_lo[3]};
  *(float4*)(oV + ob + l0_hi) = float4{av_hi[0], av_hi[1], av_hi[2], av_hi[3]};
  *(float4*)(oV + ob + l0_lo) = float4{av_lo[0], av_lo[1], av_lo[2], av_lo[3]};
}

// ---------------- fused gate + partials per (h, chunk) ----------------
__global__ __launch_bounds__(256) void gatepart_kernel(const float* __restrict__ kf,
    const float* __restrict__ vf, const float* __restrict__ wgz_w,
    const float* __restrict__ wgz_b, const float* __restrict__ kvs,
    float* __restrict__ g, float* __restrict__ A, float* __restrict__ gsum)
{
  __shared__ float MT[64][68];
  __shared__ float kb[64][68];
  __shared__ float kbT[64][68];  // kbT[t][d] transposed copy: A-accum reads become b128, conflict-free
  __shared__ float vb[64][68];
  __shared__ float yb[64][68];
  __shared__ float part[4][64];
  __shared__ float gl[64];
  int h = blockIdx.y, ch = blockIdx.x;
  int t0 = ch * 64, tid = threadIdx.x;
#pragma unroll
  for (int k = 0; k < 16; ++k) {
    int idx = tid + k * 256;
    int a = idx >> 6, b = idx & 63;
    MT[b][a] = wgz_w[idx] * kvs[idx];
    float kv = kf[(size_t)(h * 64 + a) * L_SEQ + t0 + b];
    kb[a][b] = kv;
    kbT[b][a] = kv;
    vb[a][b] = vf[(size_t)(h * 64 + a) * L_SEQ + t0 + b];
  }
  __syncthreads();
  int lg = tid & 15, dg = tid >> 4;
  {
    float acc[4][4] = {};
    for (int e = 0; e < 64; ++e) {
      float4 mv4 = *(const float4*)(&MT[e][dg * 4]);
      float4 kv4 = *(const float4*)(&kb[e][lg * 4]);
      float mvv[4] = {mv4.x, mv4.y, mv4.z, mv4.w};
      float kvv[4] = {kv4.x, kv4.y, kv4.z, kv4.w};
#pragma unroll
      for (int r = 0; r < 4; ++r)
#pragma unroll
        for (int j = 0; j < 4; ++j)
          acc[r][j] = fmaf(mvv[r], kvv[j], acc[r][j]);
    }
#pragma unroll
    for (int r = 0; r < 4; ++r)
#pragma unroll
      for (int j = 0; j < 4; ++j)
        yb[dg * 4 + r][lg * 4 + j] = acc[r][j];
  }
  __syncthreads();
  {
    int l = tid & 63, p = tid >> 6;
    float s = 0.f;
#pragma unroll
    for (int dd = 0; dd < 16; ++dd)
      s = fmaf(yb[p * 16 + dd][l], vb[p * 16 + dd][l], s);
    part[p][l] = s;
  }
  __syncthreads();
  if (tid < 64) {
    float logit = part[0][tid] + part[1][tid] + part[2][tid] + part[3][tid] + wgz_b[0];
    float rl = fmaxf(logit, 0.f);
    float gv = rl * rl + EPSF;
    g[h * L_SEQ + t0 + tid] = gv;
    gl[tid] = gv;
  }
  __syncthreads();
  // parallel gsum reduce (wave 0)
  if (tid < 64) {
    float s = gl[tid];
#pragma unroll
    for (int off = 1; off < 64; off <<= 1) s += __shfl_xor(s, off, 64);
    if (tid == 0) gsum[h * 32 + ch] = s;
  }
  int eg = tid & 15, dg2 = tid >> 4;
  float acc[4][4] = {};
  for (int t = 0; t < 64; ++t) {
    float gt = gl[t];
    float4 k4 = *(const float4*)(&kbT[t][eg * 4]);
    float kv4[4] = {k4.x * gt, k4.y * gt, k4.z * gt, k4.w * gt};
    float vv4[4];
#pragma unroll
    for (int r = 0; r < 4; ++r) vv4[r] = vb[dg2 * 4 + r][t];
#pragma unroll
    for (int r = 0; r < 4; ++r)
#pragma unroll
      for (int j = 0; j < 4; ++j)
        acc[r][j] = fmaf(vv4[r], kv4[j], acc[r][j]);
  }
  float* Ap = A + ((size_t)(h * 32 + ch)) * 4096;
#pragma unroll
  for (int r = 0; r < 4; ++r)
#pragma unroll
    for (int j = 0; j < 4; ++j)
      Ap[(dg2 * 4 + r) * 64 + eg * 4 + j] = acc[r][j];
}

// ---------------- attention: inline chunk-prefix (reads raw A, gsum) + in-chunk gated
// quadratic, /G, l2norm, bf16 store.  prefix fused: block (h,ch) sums A[h, c<ch] in
// ascending c (same rounding order as the old serial prefix kernel). ----------------
__global__ __launch_bounds__(256) void attn_kernel(const float* __restrict__ q,
    const float* __restrict__ kf, const float* __restrict__ vf, const float* __restrict__ g,
    const float* __restrict__ A, const float* __restrict__ gsum,
    __hip_bfloat16* __restrict__ sp)
{
  __shared__ float qT[64][68];
  __shared__ float SW[64][69];
  __shared__ float vb[64][68];
  __shared__ float kb[64][69];
  __shared__ float gl[64], Gs[64], rsq[64];
  int h = blockIdx.y, ch = blockIdx.x;
  int t0 = ch * 64, tid = threadIdx.x;
#pragma unroll
  for (int k = 0; k < 16; ++k) {
    int idx = tid + k * 256;
    int a = idx >> 6, b = idx & 63;
    qT[b][a] = q[(size_t)(t0 + a) * D_MODEL + h * 64 + b];
    vb[a][b] = vf[(size_t)(h * 64 + a) * L_SEQ + t0 + b];
    kb[a][b] = kf[(size_t)(h * 64 + a) * L_SEQ + t0 + b];
  }
  // Sprev = sum over previous chunks' raw states (was the prefix kernel)
  {
    float4 sacc[4] = {};
    const float* Abase = A + ((size_t)(h * 32)) * 4096 + tid * 16;
    for (int c = 0; c < ch; ++c) {
      const float* Ac = Abase + (size_t)c * 4096;
#pragma unroll
      for (int t = 0; t < 4; ++t) {
        float4 v = *(const float4*)(Ac + t * 4);
        sacc[t].x += v.x; sacc[t].y += v.y; sacc[t].z += v.z; sacc[t].w += v.w;
      }
    }
    int a0 = tid >> 2, b0 = (tid & 3) * 16;
#pragma unroll
    for (int t = 0; t < 4; ++t) {
      SW[a0][b0 + t * 4 + 0] = sacc[t].x;
      SW[a0][b0 + t * 4 + 1] = sacc[t].y;
      SW[a0][b0 + t * 4 + 2] = sacc[t].z;
      SW[a0][b0 + t * 4 + 3] = sacc[t].w;
    }
  }
  if (tid < 64) { gl[tid] = g[h * L_SEQ + t0 + tid]; rsq[tid] = 0.f; }
  __syncthreads();
  if (tid < 64) {
    // Gprev = sum of previous chunks' gate sums (was prefix over gsum)
    float gp = (tid < ch) ? gsum[h * 32 + tid] : 0.f;
#pragma unroll
    for (int off = 1; off < 64; off <<= 1) gp += __shfl_xor(gp, off, 64);
    float val = gl[tid];
#pragma unroll
    for (int off = 1; off < 64; off <<= 1) {
      float o = __shfl_up(val, (unsigned)off, 64);
      if (tid >= off) val += o;
    }
    Gs[tid] = fmaxf(gp + val, EPSF);
  }
  int lg = tid & 15, eg = tid >> 4;
  // merged loop: q@Sprev (acc) and q@v (sc) share the qT loads
  float acc[4][4] = {};
  float sc[4][4] = {};
  for (int d = 0; d < 64; ++d) {
    float4 q4 = *(const float4*)(&qT[d][lg * 4]);
    float qv[4] = {q4.x, q4.y, q4.z, q4.w};
    float sv[4];
#pragma unroll
    for (int j = 0; j < 4; ++j) sv[j] = SW[d][eg * 4 + j];
    float4 v4 = *(const float4*)(&vb[d][eg * 4]);
    float vv[4] = {v4.x, v4.y, v4.z, v4.w};
#pragma unroll
    for (int r = 0; r < 4; ++r)
#pragma unroll
      for (int j = 0; j < 4; ++j) {
        acc[r][j] = fmaf(qv[r], sv[j], acc[r][j]);
        sc[r][j] = fmaf(qv[r], vv[j], sc[r][j]);
      }
  }
  __syncthreads();
#pragma unroll
  for (int r = 0; r < 4; ++r)
#pragma unroll
    for (int m = 0; m < 4; ++m) {
      int ll = lg * 4 + r, tt = eg * 4 + m;
      SW[ll][tt] = (tt <= ll) ? sc[r][m] * gl[tt] : 0.f;
    }
  __syncthreads();
  for (int t = 0; t < 64; ++t) {
    float wv4[4], kv4[4];
#pragma unroll
    for (int r = 0; r < 4; ++r) wv4[r] = SW[lg * 4 + r][t];
#pragma unroll
    for (int j = 0; j < 4; ++j) kv4[j] = kb[eg * 4 + j][t];
#pragma unroll
    for (int r = 0; r < 4; ++r)
#pragma unroll
      for (int j = 0; j < 4; ++j)
        acc[r][j] = fmaf(wv4[r], kv4[j], acc[r][j]);
  }
  float val[4][4];
  int egw = (tid >> 4) & 3;
#pragma unroll
  for (int r = 0; r < 4; ++r) {
    float gi = 1.f / Gs[lg * 4 + r];
    float pr = 0.f;
#pragma unroll
    for (int j = 0; j < 4; ++j) { float v = acc[r][j] * gi; val[r][j] = v; pr = fmaf(v, v, pr); }
    pr += __shfl_xor(pr, 16, 64);
    pr += __shfl_xor(pr, 32, 64);
    if (egw == 0) atomicAdd(&rsq[lg * 4 + r], pr);
  }
  __syncthreads();
#pragma unroll
  for (int r = 0; r < 4; ++r) {
    float inv = 1.f / fmaxf(sqrtf(rsq[lg * 4 + r]), EPSF);
    union { ushort4 u; __hip_bfloat16 hh[4]; } pk;
#pragma unroll
    for (int j = 0; j < 4; ++j) pk.hh[j] = __float2bfloat16(val[r][j] * inv);
    *(ushort4*)(sp + (size_t)(t0 + lg * 4 + r) * D_MODEL + h * 64 + eg * 4) = pk.u;
  }
}

// ---------------- final GEMM: out = sp @ wo^T + b ----------------
__global__ __launch_bounds__(256) void gemm_out_kernel(const __hip_bfloat16* __restrict__ A,
    const __hip_bfloat16* __restrict__ W, const float* __restrict__ bias,
    float* __restrict__ O)
{
  const int N = D_MODEL, K = D_MODEL;
  int lane = threadIdx.x & 63;
  int wave = threadIdx.x >> 6;
  int m0 = blockIdx.x * 64 + wave * 16;
  int n0 = blockIdx.y * 64;
  int lrow = lane & 15, quad = lane >> 4;
  const __hip_bfloat16* Ap = A + (size_t)(m0 + lrow) * K + quad * 8;
  const __hip_bfloat16* Wp = W + (size_t)(n0 + lrow) * K + quad * 8;
  f32x4 acc[4] = {};
  for (int k0 = 0; k0 < K; k0 += 32) {
    short8 a = *(const short8*)(Ap + k0);
#pragma unroll
    for (int j = 0; j < 4; ++j) {
      short8 b = *(const short8*)(Wp + k0 + (size_t)j * 16 * K);
      acc[j] = __builtin_amdgcn_mfma_f32_16x16x32_bf16(a, b, acc[j], 0, 0, 0);
    }
  }
#pragma unroll
  for (int j = 0; j < 4; ++j) {
    int n = n0 + j * 16 + lrow;
    float bv = bias[n];
#pragma unroll
    for (int r = 0; r < 4; ++r)
      O[(size_t)(m0 + quad * 4 + r) * N + n] = acc[j][r] + bv;
  }
}

extern "C" void kernel_launch(void* const* d_in, const int* in_sizes, int n_in,
                              void* d_out, int out_size, void* d_ws, size_t ws_size,
                              hipStream_t stream) {
  const float* x = (const float*)d_in[0];
  const float* sb = (const float*)d_in[1];
  const float* wq_w = (const float*)d_in[2];
  const float* wq_b = (const float*)d_in[3];
  const float* wk_w = (const float*)d_in[4];
  const float* wk_b = (const float*)d_in[5];
  const float* wv_w = (const float*)d_in[6];
  const float* wv_b = (const float*)d_in[7];
  const float* wo_w = (const float*)d_in[8];
  const float* wo_b = (const float*)d_in[9];
  const float* td_w = (const float*)d_in[10];
  const float* td_b = (const float*)d_in[11];
  const float* wgz_w = (const float*)d_in[12];
  const float* wgz_b = (const float*)d_in[13];
  const float* kvs = (const float*)d_in[14];
  float* out = (float*)d_out;

  char* ws = (char*)d_ws;
  size_t off = 0;
  auto alloc = [&](size_t bytes) -> void* {
    void* p = ws + off;
    off += (bytes + 255) & ~(size_t)255;
    return p;
  };
  __hip_bfloat16* xb  = (__hip_bfloat16*)alloc((size_t)L_SEQ * D_MODEL * 2);
  __hip_bfloat16* sbb = (__hip_bfloat16*)alloc((size_t)L_SEQ * D_MODEL * 2);
  __hip_bfloat16* wqb = (__hip_bfloat16*)alloc((size_t)D_MODEL * D_MODEL * 2);
  __hip_bfloat16* wkb = (__hip_bfloat16*)alloc((size_t)D_MODEL * D_MODEL * 2);
  __hip_bfloat16* wvb = (__hip_bfloat16*)alloc((size_t)D_MODEL * D_MODEL * 2);
  __hip_bfloat16* tdb = (__hip_bfloat16*)alloc((size_t)D_MODEL * D_MODEL * 2);
  __hip_bfloat16* wob = (__hip_bfloat16*)alloc((size_t)D_MODEL * D_MODEL * 2);
  __hip_bfloat16* spb = (__hip_bfloat16*)alloc((size_t)L_SEQ * D_MODEL * 2);
  _Float16* ku16 = (_Float16*)alloc((size_t)D_MODEL * UPAD * 2);
  _Float16* vu16 = (_Float16*)alloc((size_t)D_MODEL * UPAD * 2);
  float* qbuf  = (float*)alloc((size_t)L_SEQ * D_MODEL * 4);
  float* fT    = (float*)alloc((size_t)D_MODEL * L_SEQ * 4);
  float* kfT   = (float*)alloc((size_t)D_MODEL * L_SEQ * 4);
  float* vfT   = (float*)alloc((size_t)D_MODEL * L_SEQ * 4);
  float* gbuf  = (float*)alloc((size_t)NH * L_SEQ * 4);
  float* gsum  = (float*)alloc((size_t)NH * 32 * 4);
  float* Abuf  = (float*)alloc((size_t)NH * 32 * 4096 * 4);

  prep_kernel<<<13568, 256, 0, stream>>>(x, sb, wq_w, wk_w, wv_w, td_w, wo_w,
                                         xb, sbb, wqb, wkb, wvb, tdb, wob,
                                         ku16, vu16);
  gemm4_kernel<<<dim3(L_SEQ / 64, D_MODEL / 64, 4), 256, 0, stream>>>(
      xb, sbb, wqb, wkb, wvb, tdb, wq_b, wk_b, wv_b, td_b, qbuf, fT,
      ku16, vu16);
  conv_kernel<<<512, 256, 0, stream>>>(ku16, vu16, fT, kfT, vfT);
  gatepart_kernel<<<dim3(32, 8), 256, 0, stream>>>(kfT, vfT, wgz_w, wgz_b, kvs, gbuf, Abuf, gsum);
  attn_kernel<<<dim3(32, 8), 256, 0, stream>>>(qbuf, kfT, vfT, gbuf, Abuf, gsum, spb);
  gemm_out_kernel<<<dim3(L_SEQ / 64, D_MODEL / 64), 256, 0, stream>>>(spb, wob, wo_b, out);
}

// Round 4
// 187.942 us; speedup vs baseline: 1.2458x; 1.0670x over previous
//
#include <hip/hip_runtime.h>
#include <hip/hip_bf16.h>
#include <hip/hip_fp16.h>

#define L_SEQ 2048
#define D_MODEL 512
#define NH 8
#define HD 64
#define EPSF 1e-5f

// u f16 layout: [512 ch][2560], logical s at col 256+s; margins zeroed.
#define UPAD 2560
#define UOFF 256
// filter LDS: 8 phase copies, stride 2120 f16 (=1060 words, == 4 mod 32 -> 2-way-free banks)
#define XLEN 2112
#define XPAD 2120

typedef __attribute__((ext_vector_type(8))) short short8;
typedef __attribute__((ext_vector_type(8))) _Float16 half8;
typedef __attribute__((ext_vector_type(4))) _Float16 half4v;
typedef __attribute__((ext_vector_type(4))) float f32x4;

// ---------------- prep: fp32->bf16 for 7 tensors + zero u16 margins ----------------
__global__ __launch_bounds__(256) void prep_kernel(const float* __restrict__ x,
    const float* __restrict__ sb, const float* __restrict__ wq, const float* __restrict__ wk,
    const float* __restrict__ wv, const float* __restrict__ td, const float* __restrict__ wo,
    __hip_bfloat16* __restrict__ xb, __hip_bfloat16* __restrict__ sbb,
    __hip_bfloat16* __restrict__ wqb, __hip_bfloat16* __restrict__ wkb,
    __hip_bfloat16* __restrict__ wvb, __hip_bfloat16* __restrict__ tdb,
    __hip_bfloat16* __restrict__ wob,
    _Float16* __restrict__ ku16, _Float16* __restrict__ vu16)
{
  int i = blockIdx.x * 256 + threadIdx.x;
  if (i < 2097152) {
    if (i < 1048576) xb[i] = __float2bfloat16(x[i]);
    else sbb[i - 1048576] = __float2bfloat16(sb[i - 1048576]);
  } else if (i < 3407872) {
    int j = i - 2097152;
    int w = j >> 18;
    int r = j & 262143;
    const float* s = (w == 0) ? wq : (w == 1) ? wk : (w == 2) ? wv : (w == 3) ? td : wo;
    __hip_bfloat16* d = (w == 0) ? wqb : (w == 1) ? wkb : (w == 2) ? wvb : (w == 3) ? tdb : wob;
    d[r] = __float2bfloat16(s[r]);
  } else if (i < 3473408) {
    // zero u16 margins: 2 arrays x 512 rows x 64 chunks of 8 f16 (16B)
    int t = i - 3407872;
    int arr = t >> 15;
    int rem = t & 32767;
    int row = rem >> 6;
    int cc = rem & 63;
    int col = (cc < 32) ? cc * 8 : 2304 + (cc - 32) * 8;
    _Float16* base = arr ? vu16 : ku16;
    *(int4*)(base + (size_t)row * UPAD + col) = int4{0, 0, 0, 0};
  }
}

// ---------------- batched GEMM: q,k,v,filters; l2norm + f16 pad-write for k,v ----------------
// K-loop fully unrolled with one-step register prefetch: next {a, b[4]} issued before the
// current step's MFMAs -> loads stay in flight under compute instead of vmcnt(0) per step.
__global__ __launch_bounds__(256) void gemm4_kernel(
    const __hip_bfloat16* __restrict__ xb, const __hip_bfloat16* __restrict__ sbb,
    const __hip_bfloat16* __restrict__ wqb, const __hip_bfloat16* __restrict__ wkb,
    const __hip_bfloat16* __restrict__ wvb, const __hip_bfloat16* __restrict__ tdb,
    const float* __restrict__ bq, const float* __restrict__ bk,
    const float* __restrict__ bv, const float* __restrict__ btd,
    float* __restrict__ qout, float* __restrict__ fT,
    _Float16* __restrict__ ku16, _Float16* __restrict__ vu16)
{
  int z = blockIdx.z;
  const __hip_bfloat16* A = (z == 3) ? sbb : xb;
  const __hip_bfloat16* W = (z == 0) ? wqb : (z == 1) ? wkb : (z == 2) ? wvb : tdb;
  const float* bias = (z == 0) ? bq : (z == 1) ? bk : (z == 2) ? bv : btd;
  const int M = L_SEQ, N = D_MODEL, K = D_MODEL;
  int lane = threadIdx.x & 63;
  int wave = threadIdx.x >> 6;
  int m0 = blockIdx.x * 64 + wave * 16;
  int n0 = blockIdx.y * 64;
  int lrow = lane & 15, quad = lane >> 4;
  const __hip_bfloat16* Ap = A + (size_t)(m0 + lrow) * K + quad * 8;
  const __hip_bfloat16* Wp = W + (size_t)(n0 + lrow) * K + quad * 8;
  f32x4 acc[4] = {};
  short8 a_cur = *(const short8*)(Ap);
  short8 b_cur[4];
#pragma unroll
  for (int j = 0; j < 4; ++j) b_cur[j] = *(const short8*)(Wp + (size_t)j * 16 * K);
#pragma unroll
  for (int k0 = 0; k0 < K; k0 += 32) {
    short8 a_nxt;
    short8 b_nxt[4];
    if (k0 + 32 < K) {
      a_nxt = *(const short8*)(Ap + k0 + 32);
#pragma unroll
      for (int j = 0; j < 4; ++j)
        b_nxt[j] = *(const short8*)(Wp + k0 + 32 + (size_t)j * 16 * K);
    } else {
      a_nxt = a_cur;
#pragma unroll
      for (int j = 0; j < 4; ++j) b_nxt[j] = b_cur[j];
    }
#pragma unroll
    for (int j = 0; j < 4; ++j)
      acc[j] = __builtin_amdgcn_mfma_f32_16x16x32_bf16(a_cur, b_cur[j], acc[j], 0, 0, 0);
    a_cur = a_nxt;
#pragma unroll
    for (int j = 0; j < 4; ++j) b_cur[j] = b_nxt[j];
  }
  float bw[4];
#pragma unroll
  for (int j = 0; j < 4; ++j) bw[j] = bias[n0 + j * 16 + lrow];
  if (z == 0) {
#pragma unroll
    for (int j = 0; j < 4; ++j)
#pragma unroll
      for (int r = 0; r < 4; ++r)
        qout[(size_t)(m0 + quad * 4 + r) * N + n0 + j * 16 + lrow] = acc[j][r] + bw[j];
  } else if (z == 3) {
#pragma unroll
    for (int j = 0; j < 4; ++j) {
      float4 ov = {acc[j][0] + bw[j], acc[j][1] + bw[j], acc[j][2] + bw[j], acc[j][3] + bw[j]};
      *(float4*)(fT + (size_t)(n0 + j * 16 + lrow) * M + m0 + quad * 4) = ov;
    }
  } else {
    float val[4][4];
#pragma unroll
    for (int j = 0; j < 4; ++j)
#pragma unroll
      for (int r = 0; r < 4; ++r) val[j][r] = acc[j][r] + bw[j];
    // l2-normalize over head dim (this block's 64 n-cols = one head)
    float pr[4];
#pragma unroll
    for (int r = 0; r < 4; ++r)
      pr[r] = val[0][r] * val[0][r] + val[1][r] * val[1][r] +
              val[2][r] * val[2][r] + val[3][r] * val[3][r];
#pragma unroll
    for (int off = 1; off < 16; off <<= 1)
#pragma unroll
      for (int r = 0; r < 4; ++r)
        pr[r] += __shfl_xor(pr[r], off, 64);
    _Float16* u16 = (z == 1) ? ku16 : vu16;
#pragma unroll
    for (int r = 0; r < 4; ++r) {
      float inv = 1.f / fmaxf(sqrtf(pr[r]), EPSF);
#pragma unroll
      for (int j = 0; j < 4; ++j) val[j][r] *= inv;
    }
#pragma unroll
    for (int j = 0; j < 4; ++j) {
      half4v pk = {(_Float16)val[j][0], (_Float16)val[j][1],
                   (_Float16)val[j][2], (_Float16)val[j][3]};
      *(half4v*)(u16 + (size_t)(n0 + j * 16 + lrow) * UPAD + UOFF + m0 + quad * 4) = pk;
    }
  }
}

// ---------------- causal conv via MFMA Toeplitz, filter in LDS (f16) ----------------
// block = 1 channel, 4 waves; wave = tile-pair {l0, 1792-l0}, BOTH tensors.
// Rotate-prefetch: next step's 2 LDS + 2 global b128 loads issue before current MFMAs.
// Loop-exit overshoot verified in-bounds (LDS addr16 <= 2119 < XPAD; u idx <= 2344 < UPAD).
__global__ __launch_bounds__(256) void conv_kernel(
    const _Float16* __restrict__ ku16, const _Float16* __restrict__ vu16,
    const float* __restrict__ fT, float* __restrict__ oK, float* __restrict__ oV)
{
  __shared__ _Float16 lds_f[8 * XPAD];
  int c = blockIdx.x;
  int tid = threadIdx.x;
  const float* Fc = fT + (size_t)c * L_SEQ;
  // stage: lds_f[p][x] = f16(F[2063 - x - p]), zero outside [0,2048)
#pragma unroll
  for (int p = 0; p < 8; ++p) {
#pragma unroll
    for (int t = 0; t < 9; ++t) {
      int xx = tid + t * 256;
      if (xx < XLEN) {
        int j = 2063 - xx - p;
        float v = (j >= 0 && j < L_SEQ) ? Fc[j] : 0.f;
        lds_f[p * XPAD + xx] = (_Float16)v;
      }
    }
  }
  __syncthreads();

  int wave = tid >> 6, lane = tid & 63;
  int pair = wave;
  int l0_lo = 256 * pair;
  int l0_hi = 1792 - l0_lo;
  int mn = lane & 15, quad = lane >> 4;

  const _Float16* puk = ku16 + (size_t)c * UPAD + 16 * mn + 8 * quad;
  const _Float16* puv = vu16 + (size_t)c * UPAD + 16 * mn + 8 * quad;

  int j0c = 2063 - mn;
  int p8 = j0c & 7;
  int xb0 = (j0c - p8) + 8 * quad;
  const _Float16* pf_hi = lds_f + p8 * XPAD + (xb0 - (l0_hi + 256));
  const _Float16* pf_lo = lds_f + p8 * XPAD + (xb0 - (l0_lo + 256));

  int steps_lo = pair * 8 + 9;
  int steps_hi = 65 - pair * 8;
  f32x4 ak_hi = {}, ak_lo = {}, av_hi = {}, av_lo = {};
  half8 bk = *(const half8*)puk;
  half8 bv = *(const half8*)puv;
  half8 fh = *(const half8*)pf_hi;
  half8 fl = *(const half8*)pf_lo;
#pragma unroll 2
  for (int i = 0; i < steps_lo; ++i) {
    puk += 32; puv += 32; pf_hi += 32; pf_lo += 32;
    half8 bk_n = *(const half8*)puk;
    half8 bv_n = *(const half8*)puv;
    half8 fh_n = *(const half8*)pf_hi;
    half8 fl_n = *(const half8*)pf_lo;
    ak_hi = __builtin_amdgcn_mfma_f32_16x16x32_f16(fh, bk, ak_hi, 0, 0, 0);
    av_hi = __builtin_amdgcn_mfma_f32_16x16x32_f16(fh, bv, av_hi, 0, 0, 0);
    ak_lo = __builtin_amdgcn_mfma_f32_16x16x32_f16(fl, bk, ak_lo, 0, 0, 0);
    av_lo = __builtin_amdgcn_mfma_f32_16x16x32_f16(fl, bv, av_lo, 0, 0, 0);
    bk = bk_n; bv = bv_n; fh = fh_n; fl = fl_n;
  }
  // bk/bv/fh now hold step steps_lo values (fl's prefetch is dead from here on)
#pragma unroll 2
  for (int i = steps_lo; i < steps_hi; ++i) {
    puk += 32; puv += 32; pf_hi += 32;
    half8 bk_n = *(const half8*)puk;
    half8 bv_n = *(const half8*)puv;
    half8 fh_n = *(const half8*)pf_hi;
    ak_hi = __builtin_amdgcn_mfma_f32_16x16x32_f16(fh, bk, ak_hi, 0, 0, 0);
    av_hi = __builtin_amdgcn_mfma_f32_16x16x32_f16(fh, bv, av_hi, 0, 0, 0);
    bk = bk_n; bv = bv_n; fh = fh_n;
  }
  size_t ob = (size_t)c * L_SEQ + 16 * mn + 4 * quad;
  *(float4*)(oK + ob + l0_hi) = float4{ak_hi[0], ak_hi[1], ak_hi[2], ak_hi[3]};
  *(float4*)(oK + ob + l0_lo) = float4{ak_lo[0], ak_lo[1], ak_lo[2], ak_lo[3]};
  *(float4*)(oV + ob + l0_hi) = float4{av_hi[0], av_hi[1], av_hi[2], av_hi[3]};
  *(float4*)(oV + ob + l0_lo) = float4{av_lo[0], av_lo[1], av_lo[2], av_lo[3]};
}

// ---------------- fused gate + partials per (h, chunk) ----------------
__global__ __launch_bounds__(256) void gatepart_kernel(const float* __restrict__ kf,
    const float* __restrict__ vf, const float* __restrict__ wgz_w,
    const float* __restrict__ wgz_b, const float* __restrict__ kvs,
    float* __restrict__ g, float* __restrict__ A, float* __restrict__ gsum)
{
  __shared__ float MT[64][68];
  __shared__ float kb[64][68];
  __shared__ float kbT[64][68];  // kbT[t][d] transposed copy: A-accum reads become b128, conflict-free
  __shared__ float vb[64][68];
  __shared__ float yb[64][68];
  __shared__ float part[4][64];
  __shared__ float gl[64];
  int h = blockIdx.y, ch = blockIdx.x;
  int t0 = ch * 64, tid = threadIdx.x;
#pragma unroll
  for (int k = 0; k < 16; ++k) {
    int idx = tid + k * 256;
    int a = idx >> 6, b = idx & 63;
    MT[b][a] = wgz_w[idx] * kvs[idx];
    float kv = kf[(size_t)(h * 64 + a) * L_SEQ + t0 + b];
    kb[a][b] = kv;
    kbT[b][a] = kv;
    vb[a][b] = vf[(size_t)(h * 64 + a) * L_SEQ + t0 + b];
  }
  __syncthreads();
  int lg = tid & 15, dg = tid >> 4;
  {
    float acc[4][4] = {};
    for (int e = 0; e < 64; ++e) {
      float4 mv4 = *(const float4*)(&MT[e][dg * 4]);
      float4 kv4 = *(const float4*)(&kb[e][lg * 4]);
      float mvv[4] = {mv4.x, mv4.y, mv4.z, mv4.w};
      float kvv[4] = {kv4.x, kv4.y, kv4.z, kv4.w};
#pragma unroll
      for (int r = 0; r < 4; ++r)
#pragma unroll
        for (int j = 0; j < 4; ++j)
          acc[r][j] = fmaf(mvv[r], kvv[j], acc[r][j]);
    }
#pragma unroll
    for (int r = 0; r < 4; ++r)
#pragma unroll
      for (int j = 0; j < 4; ++j)
        yb[dg * 4 + r][lg * 4 + j] = acc[r][j];
  }
  __syncthreads();
  {
    int l = tid & 63, p = tid >> 6;
    float s = 0.f;
#pragma unroll
    for (int dd = 0; dd < 16; ++dd)
      s = fmaf(yb[p * 16 + dd][l], vb[p * 16 + dd][l], s);
    part[p][l] = s;
  }
  __syncthreads();
  if (tid < 64) {
    float logit = part[0][tid] + part[1][tid] + part[2][tid] + part[3][tid] + wgz_b[0];
    float rl = fmaxf(logit, 0.f);
    float gv = rl * rl + EPSF;
    g[h * L_SEQ + t0 + tid] = gv;
    gl[tid] = gv;
  }
  __syncthreads();
  // parallel gsum reduce (wave 0)
  if (tid < 64) {
    float s = gl[tid];
#pragma unroll
    for (int off = 1; off < 64; off <<= 1) s += __shfl_xor(s, off, 64);
    if (tid == 0) gsum[h * 32 + ch] = s;
  }
  int eg = tid & 15, dg2 = tid >> 4;
  float acc[4][4] = {};
  for (int t = 0; t < 64; ++t) {
    float gt = gl[t];
    float4 k4 = *(const float4*)(&kbT[t][eg * 4]);
    float kv4[4] = {k4.x * gt, k4.y * gt, k4.z * gt, k4.w * gt};
    float vv4[4];
#pragma unroll
    for (int r = 0; r < 4; ++r) vv4[r] = vb[dg2 * 4 + r][t];
#pragma unroll
    for (int r = 0; r < 4; ++r)
#pragma unroll
      for (int j = 0; j < 4; ++j)
        acc[r][j] = fmaf(vv4[r], kv4[j], acc[r][j]);
  }
  float* Ap = A + ((size_t)(h * 32 + ch)) * 4096;
#pragma unroll
  for (int r = 0; r < 4; ++r)
#pragma unroll
    for (int j = 0; j < 4; ++j)
      Ap[(dg2 * 4 + r) * 64 + eg * 4 + j] = acc[r][j];
}

// ---------------- exclusive prefix over 32 chunks (in place), ILP version ----------------
// All 32 chunk loads hoisted (independent, in flight together) instead of a serial
// dependent-load walk; then register prefix + stores. Each thread owns its (h,de) column.
__global__ void prefix_kernel(float* __restrict__ A, float* __restrict__ gsum)
{
  int flat = blockIdx.x * 256 + threadIdx.x;
  int h = flat >> 12, de = flat & 4095;
  size_t base = (size_t)h * 32 * 4096 + de;
  float v[32];
#pragma unroll
  for (int c = 0; c < 32; ++c) v[c] = A[base + (size_t)c * 4096];
  float run = 0.f;
#pragma unroll
  for (int c = 0; c < 32; ++c) {
    A[base + (size_t)c * 4096] = run;
    run += v[c];
  }
  if (flat < 8) {
    float t[32];
#pragma unroll
    for (int c = 0; c < 32; ++c) t[c] = gsum[flat * 32 + c];
    float r = 0.f;
#pragma unroll
    for (int c = 0; c < 32; ++c) { gsum[flat * 32 + c] = r; r += t[c]; }
  }
}

// ---------------- attention: carry + in-chunk gated quadratic, /G, l2norm, bf16 store ----------------
__global__ __launch_bounds__(256) void attn_kernel(const float* __restrict__ q,
    const float* __restrict__ kf, const float* __restrict__ vf, const float* __restrict__ g,
    const float* __restrict__ Sprev, const float* __restrict__ Gprev,
    __hip_bfloat16* __restrict__ sp)
{
  __shared__ float qT[64][68];
  __shared__ float SW[64][69];
  __shared__ float vb[64][68];
  __shared__ float kb[64][69];
  __shared__ float gl[64], Gs[64], rsq[64];
  int h = blockIdx.y, ch = blockIdx.x;
  int t0 = ch * 64, tid = threadIdx.x;
  const float* Sp = Sprev + ((size_t)(h * 32 + ch)) * 4096;
#pragma unroll
  for (int k = 0; k < 16; ++k) {
    int idx = tid + k * 256;
    int a = idx >> 6, b = idx & 63;
    qT[b][a] = q[(size_t)(t0 + a) * D_MODEL + h * 64 + b];
    SW[a][b] = Sp[idx];
    vb[a][b] = vf[(size_t)(h * 64 + a) * L_SEQ + t0 + b];
    kb[a][b] = kf[(size_t)(h * 64 + a) * L_SEQ + t0 + b];
  }
  if (tid < 64) { gl[tid] = g[h * L_SEQ + t0 + tid]; rsq[tid] = 0.f; }
  __syncthreads();
  if (tid < 64) {
    float val = gl[tid];
#pragma unroll
    for (int off = 1; off < 64; off <<= 1) {
      float o = __shfl_up(val, (unsigned)off, 64);
      if (tid >= off) val += o;
    }
    Gs[tid] = fmaxf(Gprev[h * 32 + ch] + val, EPSF);
  }
  int lg = tid & 15, eg = tid >> 4;
  // merged loop: q@Sprev (acc) and q@v (sc) share the qT loads
  float acc[4][4] = {};
  float sc[4][4] = {};
  for (int d = 0; d < 64; ++d) {
    float4 q4 = *(const float4*)(&qT[d][lg * 4]);
    float qv[4] = {q4.x, q4.y, q4.z, q4.w};
    float sv[4];
#pragma unroll
    for (int j = 0; j < 4; ++j) sv[j] = SW[d][eg * 4 + j];
    float4 v4 = *(const float4*)(&vb[d][eg * 4]);
    float vv[4] = {v4.x, v4.y, v4.z, v4.w};
#pragma unroll
    for (int r = 0; r < 4; ++r)
#pragma unroll
      for (int j = 0; j < 4; ++j) {
        acc[r][j] = fmaf(qv[r], sv[j], acc[r][j]);
        sc[r][j] = fmaf(qv[r], vv[j], sc[r][j]);
      }
  }
  __syncthreads();
#pragma unroll
  for (int r = 0; r < 4; ++r)
#pragma unroll
    for (int m = 0; m < 4; ++m) {
      int ll = lg * 4 + r, tt = eg * 4 + m;
      SW[ll][tt] = (tt <= ll) ? sc[r][m] * gl[tt] : 0.f;
    }
  __syncthreads();
  for (int t = 0; t < 64; ++t) {
    float wv4[4], kv4[4];
#pragma unroll
    for (int r = 0; r < 4; ++r) wv4[r] = SW[lg * 4 + r][t];
#pragma unroll
    for (int j = 0; j < 4; ++j) kv4[j] = kb[eg * 4 + j][t];
#pragma unroll
    for (int r = 0; r < 4; ++r)
#pragma unroll
      for (int j = 0; j < 4; ++j)
        acc[r][j] = fmaf(wv4[r], kv4[j], acc[r][j]);
  }
  float val[4][4];
  int egw = (tid >> 4) & 3;
#pragma unroll
  for (int r = 0; r < 4; ++r) {
    float gi = 1.f / Gs[lg * 4 + r];
    float pr = 0.f;
#pragma unroll
    for (int j = 0; j < 4; ++j) { float v = acc[r][j] * gi; val[r][j] = v; pr = fmaf(v, v, pr); }
    pr += __shfl_xor(pr, 16, 64);
    pr += __shfl_xor(pr, 32, 64);
    if (egw == 0) atomicAdd(&rsq[lg * 4 + r], pr);
  }
  __syncthreads();
#pragma unroll
  for (int r = 0; r < 4; ++r) {
    float inv = 1.f / fmaxf(sqrtf(rsq[lg * 4 + r]), EPSF);
    union { ushort4 u; __hip_bfloat16 hh[4]; } pk;
#pragma unroll
    for (int j = 0; j < 4; ++j) pk.hh[j] = __float2bfloat16(val[r][j] * inv);
    *(ushort4*)(sp + (size_t)(t0 + lg * 4 + r) * D_MODEL + h * 64 + eg * 4) = pk.u;
  }
}

// ---------------- final GEMM: out = sp @ wo^T + b (prefetched K-loop) ----------------
__global__ __launch_bounds__(256) void gemm_out_kernel(const __hip_bfloat16* __restrict__ A,
    const __hip_bfloat16* __restrict__ W, const float* __restrict__ bias,
    float* __restrict__ O)
{
  const int N = D_MODEL, K = D_MODEL;
  int lane = threadIdx.x & 63;
  int wave = threadIdx.x >> 6;
  int m0 = blockIdx.x * 64 + wave * 16;
  int n0 = blockIdx.y * 64;
  int lrow = lane & 15, quad = lane >> 4;
  const __hip_bfloat16* Ap = A + (size_t)(m0 + lrow) * K + quad * 8;
  const __hip_bfloat16* Wp = W + (size_t)(n0 + lrow) * K + quad * 8;
  f32x4 acc[4] = {};
  short8 a_cur = *(const short8*)(Ap);
  short8 b_cur[4];
#pragma unroll
  for (int j = 0; j < 4; ++j) b_cur[j] = *(const short8*)(Wp + (size_t)j * 16 * K);
#pragma unroll
  for (int k0 = 0; k0 < K; k0 += 32) {
    short8 a_nxt;
    short8 b_nxt[4];
    if (k0 + 32 < K) {
      a_nxt = *(const short8*)(Ap + k0 + 32);
#pragma unroll
      for (int j = 0; j < 4; ++j)
        b_nxt[j] = *(const short8*)(Wp + k0 + 32 + (size_t)j * 16 * K);
    } else {
      a_nxt = a_cur;
#pragma unroll
      for (int j = 0; j < 4; ++j) b_nxt[j] = b_cur[j];
    }
#pragma unroll
    for (int j = 0; j < 4; ++j)
      acc[j] = __builtin_amdgcn_mfma_f32_16x16x32_bf16(a_cur, b_cur[j], acc[j], 0, 0, 0);
    a_cur = a_nxt;
#pragma unroll
    for (int j = 0; j < 4; ++j) b_cur[j] = b_nxt[j];
  }
#pragma unroll
  for (int j = 0; j < 4; ++j) {
    int n = n0 + j * 16 + lrow;
    float bv = bias[n];
#pragma unroll
    for (int r = 0; r < 4; ++r)
      O[(size_t)(m0 + quad * 4 + r) * N + n] = acc[j][r] + bv;
  }
}

extern "C" void kernel_launch(void* const* d_in, const int* in_sizes, int n_in,
                              void* d_out, int out_size, void* d_ws, size_t ws_size,
                              hipStream_t stream) {
  const float* x = (const float*)d_in[0];
  const float* sb = (const float*)d_in[1];
  const float* wq_w = (const float*)d_in[2];
  const float* wq_b = (const float*)d_in[3];
  const float* wk_w = (const float*)d_in[4];
  const float* wk_b = (const float*)d_in[5];
  const float* wv_w = (const float*)d_in[6];
  const float* wv_b = (const float*)d_in[7];
  const float* wo_w = (const float*)d_in[8];
  const float* wo_b = (const float*)d_in[9];
  const float* td_w = (const float*)d_in[10];
  const float* td_b = (const float*)d_in[11];
  const float* wgz_w = (const float*)d_in[12];
  const float* wgz_b = (const float*)d_in[13];
  const float* kvs = (const float*)d_in[14];
  float* out = (float*)d_out;

  char* ws = (char*)d_ws;
  size_t off = 0;
  auto alloc = [&](size_t bytes) -> void* {
    void* p = ws + off;
    off += (bytes + 255) & ~(size_t)255;
    return p;
  };
  __hip_bfloat16* xb  = (__hip_bfloat16*)alloc((size_t)L_SEQ * D_MODEL * 2);
  __hip_bfloat16* sbb = (__hip_bfloat16*)alloc((size_t)L_SEQ * D_MODEL * 2);
  __hip_bfloat16* wqb = (__hip_bfloat16*)alloc((size_t)D_MODEL * D_MODEL * 2);
  __hip_bfloat16* wkb = (__hip_bfloat16*)alloc((size_t)D_MODEL * D_MODEL * 2);
  __hip_bfloat16* wvb = (__hip_bfloat16*)alloc((size_t)D_MODEL * D_MODEL * 2);
  __hip_bfloat16* tdb = (__hip_bfloat16*)alloc((size_t)D_MODEL * D_MODEL * 2);
  __hip_bfloat16* wob = (__hip_bfloat16*)alloc((size_t)D_MODEL * D_MODEL * 2);
  __hip_bfloat16* spb = (__hip_bfloat16*)alloc((size_t)L_SEQ * D_MODEL * 2);
  _Float16* ku16 = (_Float16*)alloc((size_t)D_MODEL * UPAD * 2);
  _Float16* vu16 = (_Float16*)alloc((size_t)D_MODEL * UPAD * 2);
  float* qbuf  = (float*)alloc((size_t)L_SEQ * D_MODEL * 4);
  float* fT    = (float*)alloc((size_t)D_MODEL * L_SEQ * 4);
  float* kfT   = (float*)alloc((size_t)D_MODEL * L_SEQ * 4);
  float* vfT   = (float*)alloc((size_t)D_MODEL * L_SEQ * 4);
  float* gbuf  = (float*)alloc((size_t)NH * L_SEQ * 4);
  float* gsum  = (float*)alloc((size_t)NH * 32 * 4);
  float* Abuf  = (float*)alloc((size_t)NH * 32 * 4096 * 4);

  prep_kernel<<<13568, 256, 0, stream>>>(x, sb, wq_w, wk_w, wv_w, td_w, wo_w,
                                         xb, sbb, wqb, wkb, wvb, tdb, wob,
                                         ku16, vu16);
  gemm4_kernel<<<dim3(L_SEQ / 64, D_MODEL / 64, 4), 256, 0, stream>>>(
      xb, sbb, wqb, wkb, wvb, tdb, wq_b, wk_b, wv_b, td_b, qbuf, fT,
      ku16, vu16);
  conv_kernel<<<512, 256, 0, stream>>>(ku16, vu16, fT, kfT, vfT);
  gatepart_kernel<<<dim3(32, 8), 256, 0, stream>>>(kfT, vfT, wgz_w, wgz_b, kvs, gbuf, Abuf, gsum);
  prefix_kernel<<<128, 256, 0, stream>>>(Abuf, gsum);
  attn_kernel<<<dim3(32, 8), 256, 0, stream>>>(qbuf, kfT, vfT, gbuf, Abuf, gsum, spb);
  gemm_out_kernel<<<dim3(L_SEQ / 64, D_MODEL / 64), 256, 0, stream>>>(spb, wob, wo_b, out);
}

// Round 6
// 156.640 us; speedup vs baseline: 1.4947x; 1.1998x over previous
//
#include <hip/hip_runtime.h>
#include <hip/hip_bf16.h>
#include <hip/hip_fp16.h>

#define L_SEQ 2048
#define D_MODEL 512
#define NH 8
#define HD 64
#define EPSF 1e-5f

// u f16 layout: [512 ch][2560], logical s at col 256+s; margins zeroed.
#define UPAD 2560
#define UOFF 256
// filter LDS: 8 phase copies, stride 2120 f16 (=1060 words, == 4 mod 32 -> 2-way-free banks)
#define XLEN 2112
#define XPAD 2120

// staged-GEMM LDS: row stride 72 shorts (144B) -> per-b128-wave-read exactly 8 words/bank
#define GST 72

typedef __attribute__((ext_vector_type(8))) short short8;
typedef __attribute__((ext_vector_type(8))) _Float16 half8;
typedef __attribute__((ext_vector_type(4))) _Float16 half4v;
typedef __attribute__((ext_vector_type(4))) float f32x4;

// ---------------- prep: fp32->bf16 for 7 tensors + zero u16 margins ----------------
__global__ __launch_bounds__(256) void prep_kernel(const float* __restrict__ x,
    const float* __restrict__ sb, const float* __restrict__ wq, const float* __restrict__ wk,
    const float* __restrict__ wv, const float* __restrict__ td, const float* __restrict__ wo,
    __hip_bfloat16* __restrict__ xb, __hip_bfloat16* __restrict__ sbb,
    __hip_bfloat16* __restrict__ wqb, __hip_bfloat16* __restrict__ wkb,
    __hip_bfloat16* __restrict__ wvb, __hip_bfloat16* __restrict__ tdb,
    __hip_bfloat16* __restrict__ wob,
    _Float16* __restrict__ ku16, _Float16* __restrict__ vu16)
{
  int i = blockIdx.x * 256 + threadIdx.x;
  if (i < 2097152) {
    if (i < 1048576) xb[i] = __float2bfloat16(x[i]);
    else sbb[i - 1048576] = __float2bfloat16(sb[i - 1048576]);
  } else if (i < 3407872) {
    int j = i - 2097152;
    int w = j >> 18;
    int r = j & 262143;
    const float* s = (w == 0) ? wq : (w == 1) ? wk : (w == 2) ? wv : (w == 3) ? td : wo;
    __hip_bfloat16* d = (w == 0) ? wqb : (w == 1) ? wkb : (w == 2) ? wvb : (w == 3) ? tdb : wob;
    d[r] = __float2bfloat16(s[r]);
  } else if (i < 3473408) {
    // zero u16 margins: 2 arrays x 512 rows x 64 chunks of 8 f16 (16B)
    int t = i - 3407872;
    int arr = t >> 15;
    int rem = t & 32767;
    int row = rem >> 6;
    int cc = rem & 63;
    int col = (cc < 32) ? cc * 8 : 2304 + (cc - 32) * 8;
    _Float16* base = arr ? vu16 : ku16;
    *(int4*)(base + (size_t)row * UPAD + col) = int4{0, 0, 0, 0};
  }
}

// ---------------- batched GEMM: q,k,v,filters; LDS-staged 2-phase pipeline ----------------
// Block = 64m x 64n, K=512 in 8 tiles of BK=64, A+W tiles double-buffered in LDS.
// W panel loaded once per BLOCK (was once per wave = 4x redundant). One barrier/iter;
// next-tile global loads issued after the barrier so they fly under the compute phase.
__global__ __launch_bounds__(256) void gemm4_kernel(
    const __hip_bfloat16* __restrict__ xb, const __hip_bfloat16* __restrict__ sbb,
    const __hip_bfloat16* __restrict__ wqb, const __hip_bfloat16* __restrict__ wkb,
    const __hip_bfloat16* __restrict__ wvb, const __hip_bfloat16* __restrict__ tdb,
    const float* __restrict__ bq, const float* __restrict__ bk,
    const float* __restrict__ bv, const float* __restrict__ btd,
    float* __restrict__ qout, float* __restrict__ fT,
    _Float16* __restrict__ ku16, _Float16* __restrict__ vu16)
{
  __shared__ __align__(16) short lds_s[2][2][64 * GST];
  int z = blockIdx.z;
  const __hip_bfloat16* A = (z == 3) ? sbb : xb;
  const __hip_bfloat16* W = (z == 0) ? wqb : (z == 1) ? wkb : (z == 2) ? wvb : tdb;
  const float* bias = (z == 0) ? bq : (z == 1) ? bk : (z == 2) ? bv : btd;
  const int M = L_SEQ, N = D_MODEL, K = D_MODEL;
  int tid = threadIdx.x;
  int lane = tid & 63;
  int wave = tid >> 6;
  int m_base = blockIdx.x * 64;
  int n_base = blockIdx.y * 64;
  int m0 = m_base + wave * 16;
  int n0 = n_base;
  int lrow = lane & 15, quad = lane >> 4;

  // staging decomposition: 512 chunks of 16B per tile; thread owns chunks {tid, tid+256}
  int r0 = tid >> 3, o0 = (tid & 7) * 8;
  int r1 = (tid + 256) >> 3, o1 = (tid & 7) * 8;  // (tid+256)&7 == tid&7
  const short* Ag0 = (const short*)A + (size_t)(m_base + r0) * K + o0;
  const short* Ag1 = (const short*)A + (size_t)(m_base + r1) * K + o1;
  const short* Wg0 = (const short*)W + (size_t)(n_base + r0) * K + o0;
  const short* Wg1 = (const short*)W + (size_t)(n_base + r1) * K + o1;
  int la0 = r0 * GST + o0;
  int la1 = r1 * GST + o1;

  f32x4 acc[4] = {};
  // prologue: tile 0 into regs
  short8 ra0 = *(const short8*)(Ag0);
  short8 ra1 = *(const short8*)(Ag1);
  short8 rw0 = *(const short8*)(Wg0);
  short8 rw1 = *(const short8*)(Wg1);
#pragma unroll
  for (int t = 0; t < 8; ++t) {
    const int buf = t & 1;
    *(short8*)(&lds_s[buf][0][la0]) = ra0;
    *(short8*)(&lds_s[buf][0][la1]) = ra1;
    *(short8*)(&lds_s[buf][1][la0]) = rw0;
    *(short8*)(&lds_s[buf][1][la1]) = rw1;
    __syncthreads();
    if (t < 7) {
      ra0 = *(const short8*)(Ag0 + (t + 1) * 64);
      ra1 = *(const short8*)(Ag1 + (t + 1) * 64);
      rw0 = *(const short8*)(Wg0 + (t + 1) * 64);
      rw1 = *(const short8*)(Wg1 + (t + 1) * 64);
    }
    const short* As = lds_s[buf][0];
    const short* Ws = lds_s[buf][1];
#pragma unroll
    for (int kk = 0; kk < 2; ++kk) {
      short8 a = *(const short8*)(As + (wave * 16 + lrow) * GST + kk * 32 + quad * 8);
#pragma unroll
      for (int j = 0; j < 4; ++j) {
        short8 b = *(const short8*)(Ws + (j * 16 + lrow) * GST + kk * 32 + quad * 8);
        acc[j] = __builtin_amdgcn_mfma_f32_16x16x32_bf16(a, b, acc[j], 0, 0, 0);
      }
    }
  }
  float bw[4];
#pragma unroll
  for (int j = 0; j < 4; ++j) bw[j] = bias[n0 + j * 16 + lrow];
  if (z == 0) {
#pragma unroll
    for (int j = 0; j < 4; ++j)
#pragma unroll
      for (int r = 0; r < 4; ++r)
        qout[(size_t)(m0 + quad * 4 + r) * N + n0 + j * 16 + lrow] = acc[j][r] + bw[j];
  } else if (z == 3) {
#pragma unroll
    for (int j = 0; j < 4; ++j) {
      float4 ov = {acc[j][0] + bw[j], acc[j][1] + bw[j], acc[j][2] + bw[j], acc[j][3] + bw[j]};
      *(float4*)(fT + (size_t)(n0 + j * 16 + lrow) * M + m0 + quad * 4) = ov;
    }
  } else {
    float val[4][4];
#pragma unroll
    for (int j = 0; j < 4; ++j)
#pragma unroll
      for (int r = 0; r < 4; ++r) val[j][r] = acc[j][r] + bw[j];
    // l2-normalize over head dim (this block's 64 n-cols = one head)
    float pr[4];
#pragma unroll
    for (int r = 0; r < 4; ++r)
      pr[r] = val[0][r] * val[0][r] + val[1][r] * val[1][r] +
              val[2][r] * val[2][r] + val[3][r] * val[3][r];
#pragma unroll
    for (int off = 1; off < 16; off <<= 1)
#pragma unroll
      for (int r = 0; r < 4; ++r)
        pr[r] += __shfl_xor(pr[r], off, 64);
    _Float16* u16 = (z == 1) ? ku16 : vu16;
#pragma unroll
    for (int r = 0; r < 4; ++r) {
      float inv = 1.f / fmaxf(sqrtf(pr[r]), EPSF);
#pragma unroll
      for (int j = 0; j < 4; ++j) val[j][r] *= inv;
    }
#pragma unroll
    for (int j = 0; j < 4; ++j) {
      half4v pk = {(_Float16)val[j][0], (_Float16)val[j][1],
                   (_Float16)val[j][2], (_Float16)val[j][3]};
      *(half4v*)(u16 + (size_t)(n0 + j * 16 + lrow) * UPAD + UOFF + m0 + quad * 4) = pk;
    }
  }
}

// ---------------- causal conv via MFMA Toeplitz, filter in LDS (f16) ----------------
// block = 1 channel, 4 waves; wave = tile-pair {l0, 1792-l0}, BOTH tensors.
// Rotate-prefetch: next step's 2 LDS + 2 global b128 loads issue before current MFMAs.
// Loop-exit overshoot verified in-bounds (LDS addr16 <= 2119 < XPAD; u idx <= 2344 < UPAD).
__global__ __launch_bounds__(256) void conv_kernel(
    const _Float16* __restrict__ ku16, const _Float16* __restrict__ vu16,
    const float* __restrict__ fT, float* __restrict__ oK, float* __restrict__ oV)
{
  __shared__ _Float16 lds_f[8 * XPAD];
  int c = blockIdx.x;
  int tid = threadIdx.x;
  const float* Fc = fT + (size_t)c * L_SEQ;
  // stage: lds_f[p][x] = f16(F[2063 - x - p]), zero outside [0,2048)
#pragma unroll
  for (int p = 0; p < 8; ++p) {
#pragma unroll
    for (int t = 0; t < 9; ++t) {
      int xx = tid + t * 256;
      if (xx < XLEN) {
        int j = 2063 - xx - p;
        float v = (j >= 0 && j < L_SEQ) ? Fc[j] : 0.f;
        lds_f[p * XPAD + xx] = (_Float16)v;
      }
    }
  }
  __syncthreads();

  int wave = tid >> 6, lane = tid & 63;
  int pair = wave;
  int l0_lo = 256 * pair;
  int l0_hi = 1792 - l0_lo;
  int mn = lane & 15, quad = lane >> 4;

  const _Float16* puk = ku16 + (size_t)c * UPAD + 16 * mn + 8 * quad;
  const _Float16* puv = vu16 + (size_t)c * UPAD + 16 * mn + 8 * quad;

  int j0c = 2063 - mn;
  int p8 = j0c & 7;
  int xb0 = (j0c - p8) + 8 * quad;
  const _Float16* pf_hi = lds_f + p8 * XPAD + (xb0 - (l0_hi + 256));
  const _Float16* pf_lo = lds_f + p8 * XPAD + (xb0 - (l0_lo + 256));

  int steps_lo = pair * 8 + 9;
  int steps_hi = 65 - pair * 8;
  f32x4 ak_hi = {}, ak_lo = {}, av_hi = {}, av_lo = {};
  half8 bk = *(const half8*)puk;
  half8 bv = *(const half8*)puv;
  half8 fh = *(const half8*)pf_hi;
  half8 fl = *(const half8*)pf_lo;
#pragma unroll 2
  for (int i = 0; i < steps_lo; ++i) {
    puk += 32; puv += 32; pf_hi += 32; pf_lo += 32;
    half8 bk_n = *(const half8*)puk;
    half8 bv_n = *(const half8*)puv;
    half8 fh_n = *(const half8*)pf_hi;
    half8 fl_n = *(const half8*)pf_lo;
    ak_hi = __builtin_amdgcn_mfma_f32_16x16x32_f16(fh, bk, ak_hi, 0, 0, 0);
    av_hi = __builtin_amdgcn_mfma_f32_16x16x32_f16(fh, bv, av_hi, 0, 0, 0);
    ak_lo = __builtin_amdgcn_mfma_f32_16x16x32_f16(fl, bk, ak_lo, 0, 0, 0);
    av_lo = __builtin_amdgcn_mfma_f32_16x16x32_f16(fl, bv, av_lo, 0, 0, 0);
    bk = bk_n; bv = bv_n; fh = fh_n; fl = fl_n;
  }
  // bk/bv/fh now hold step steps_lo values (fl's prefetch is dead from here on)
#pragma unroll 2
  for (int i = steps_lo; i < steps_hi; ++i) {
    puk += 32; puv += 32; pf_hi += 32;
    half8 bk_n = *(const half8*)puk;
    half8 bv_n = *(const half8*)puv;
    half8 fh_n = *(const half8*)pf_hi;
    ak_hi = __builtin_amdgcn_mfma_f32_16x16x32_f16(fh, bk, ak_hi, 0, 0, 0);
    av_hi = __builtin_amdgcn_mfma_f32_16x16x32_f16(fh, bv, av_hi, 0, 0, 0);
    bk = bk_n; bv = bv_n; fh = fh_n;
  }
  size_t ob = (size_t)c * L_SEQ + 16 * mn + 4 * quad;
  *(float4*)(oK + ob + l0_hi) = float4{ak_hi[0], ak_hi[1], ak_hi[2], ak_hi[3]};
  *(float4*)(oK + ob + l0_lo) = float4{ak_lo[0], ak_lo[1], ak_lo[2], ak_lo[3]};
  *(float4*)(oV + ob + l0_hi) = float4{av_hi[0], av_hi[1], av_hi[2], av_hi[3]};
  *(float4*)(oV + ob + l0_lo) = float4{av_lo[0], av_lo[1], av_lo[2], av_lo[3]};
}

// ---------------- fused gate + partials per (h, chunk) ----------------
__global__ __launch_bounds__(256) void gatepart_kernel(const float* __restrict__ kf,
    const float* __restrict__ vf, const float* __restrict__ wgz_w,
    const float* __restrict__ wgz_b, const float* __restrict__ kvs,
    float* __restrict__ g, float* __restrict__ A, float* __restrict__ gsum)
{
  __shared__ float MT[64][68];
  __shared__ float kb[64][68];
  __shared__ float kbT[64][68];  // kbT[t][d] transposed copy: A-accum reads become b128, conflict-free
  __shared__ float vb[64][68];
  __shared__ float yb[64][68];
  __shared__ float part[4][64];
  __shared__ float gl[64];
  int h = blockIdx.y, ch = blockIdx.x;
  int t0 = ch * 64, tid = threadIdx.x;
#pragma unroll
  for (int k = 0; k < 16; ++k) {
    int idx = tid + k * 256;
    int a = idx >> 6, b = idx & 63;
    MT[b][a] = wgz_w[idx] * kvs[idx];
    float kv = kf[(size_t)(h * 64 + a) * L_SEQ + t0 + b];
    kb[a][b] = kv;
    kbT[b][a] = kv;
    vb[a][b] = vf[(size_t)(h * 64 + a) * L_SEQ + t0 + b];
  }
  __syncthreads();
  int lg = tid & 15, dg = tid >> 4;
  {
    float acc[4][4] = {};
    for (int e = 0; e < 64; ++e) {
      float4 mv4 = *(const float4*)(&MT[e][dg * 4]);
      float4 kv4 = *(const float4*)(&kb[e][lg * 4]);
      float mvv[4] = {mv4.x, mv4.y, mv4.z, mv4.w};
      float kvv[4] = {kv4.x, kv4.y, kv4.z, kv4.w};
#pragma unroll
      for (int r = 0; r < 4; ++r)
#pragma unroll
        for (int j = 0; j < 4; ++j)
          acc[r][j] = fmaf(mvv[r], kvv[j], acc[r][j]);
    }
#pragma unroll
    for (int r = 0; r < 4; ++r)
#pragma unroll
      for (int j = 0; j < 4; ++j)
        yb[dg * 4 + r][lg * 4 + j] = acc[r][j];
  }
  __syncthreads();
  {
    int l = tid & 63, p = tid >> 6;
    float s = 0.f;
#pragma unroll
    for (int dd = 0; dd < 16; ++dd)
      s = fmaf(yb[p * 16 + dd][l], vb[p * 16 + dd][l], s);
    part[p][l] = s;
  }
  __syncthreads();
  if (tid < 64) {
    float logit = part[0][tid] + part[1][tid] + part[2][tid] + part[3][tid] + wgz_b[0];
    float rl = fmaxf(logit, 0.f);
    float gv = rl * rl + EPSF;
    g[h * L_SEQ + t0 + tid] = gv;
    gl[tid] = gv;
  }
  __syncthreads();
  // parallel gsum reduce (wave 0)
  if (tid < 64) {
    float s = gl[tid];
#pragma unroll
    for (int off = 1; off < 64; off <<= 1) s += __shfl_xor(s, off, 64);
    if (tid == 0) gsum[h * 32 + ch] = s;
  }
  int eg = tid & 15, dg2 = tid >> 4;
  float acc[4][4] = {};
  for (int t = 0; t < 64; ++t) {
    float gt = gl[t];
    float4 k4 = *(const float4*)(&kbT[t][eg * 4]);
    float kv4[4] = {k4.x * gt, k4.y * gt, k4.z * gt, k4.w * gt};
    float vv4[4];
#pragma unroll
    for (int r = 0; r < 4; ++r) vv4[r] = vb[dg2 * 4 + r][t];
#pragma unroll
    for (int r = 0; r < 4; ++r)
#pragma unroll
      for (int j = 0; j < 4; ++j)
        acc[r][j] = fmaf(vv4[r], kv4[j], acc[r][j]);
  }
  float* Ap = A + ((size_t)(h * 32 + ch)) * 4096;
#pragma unroll
  for (int r = 0; r < 4; ++r)
#pragma unroll
    for (int j = 0; j < 4; ++j)
      Ap[(dg2 * 4 + r) * 64 + eg * 4 + j] = acc[r][j];
}

// ---------------- exclusive prefix over 32 chunks (in place), ILP version ----------------
__global__ void prefix_kernel(float* __restrict__ A, float* __restrict__ gsum)
{
  int flat = blockIdx.x * 256 + threadIdx.x;
  int h = flat >> 12, de = flat & 4095;
  size_t base = (size_t)h * 32 * 4096 + de;
  float v[32];
#pragma unroll
  for (int c = 0; c < 32; ++c) v[c] = A[base + (size_t)c * 4096];
  float run = 0.f;
#pragma unroll
  for (int c = 0; c < 32; ++c) {
    A[base + (size_t)c * 4096] = run;
    run += v[c];
  }
  if (flat < 8) {
    float t[32];
#pragma unroll
    for (int c = 0; c < 32; ++c) t[c] = gsum[flat * 32 + c];
    float r = 0.f;
#pragma unroll
    for (int c = 0; c < 32; ++c) { gsum[flat * 32 + c] = r; r += t[c]; }
  }
}

// ---------------- attention: carry + in-chunk gated quadratic, /G, l2norm, bf16 store ----------------
__global__ __launch_bounds__(256) void attn_kernel(const float* __restrict__ q,
    const float* __restrict__ kf, const float* __restrict__ vf, const float* __restrict__ g,
    const float* __restrict__ Sprev, const float* __restrict__ Gprev,
    __hip_bfloat16* __restrict__ sp)
{
  __shared__ float qT[64][68];
  __shared__ float SW[64][69];
  __shared__ float vb[64][68];
  __shared__ float kb[64][69];
  __shared__ float gl[64], Gs[64], rsq[64];
  int h = blockIdx.y, ch = blockIdx.x;
  int t0 = ch * 64, tid = threadIdx.x;
  const float* Sp = Sprev + ((size_t)(h * 32 + ch)) * 4096;
#pragma unroll
  for (int k = 0; k < 16; ++k) {
    int idx = tid + k * 256;
    int a = idx >> 6, b = idx & 63;
    qT[b][a] = q[(size_t)(t0 + a) * D_MODEL + h * 64 + b];
    SW[a][b] = Sp[idx];
    vb[a][b] = vf[(size_t)(h * 64 + a) * L_SEQ + t0 + b];
    kb[a][b] = kf[(size_t)(h * 64 + a) * L_SEQ + t0 + b];
  }
  if (tid < 64) { gl[tid] = g[h * L_SEQ + t0 + tid]; rsq[tid] = 0.f; }
  __syncthreads();
  if (tid < 64) {
    float val = gl[tid];
#pragma unroll
    for (int off = 1; off < 64; off <<= 1) {
      float o = __shfl_up(val, (unsigned)off, 64);
      if (tid >= off) val += o;
    }
    Gs[tid] = fmaxf(Gprev[h * 32 + ch] + val, EPSF);
  }
  int lg = tid & 15, eg = tid >> 4;
  // merged loop: q@Sprev (acc) and q@v (sc) share the qT loads
  float acc[4][4] = {};
  float sc[4][4] = {};
  for (int d = 0; d < 64; ++d) {
    float4 q4 = *(const float4*)(&qT[d][lg * 4]);
    float qv[4] = {q4.x, q4.y, q4.z, q4.w};
    float sv[4];
#pragma unroll
    for (int j = 0; j < 4; ++j) sv[j] = SW[d][eg * 4 + j];
    float4 v4 = *(const float4*)(&vb[d][eg * 4]);
    float vv[4] = {v4.x, v4.y, v4.z, v4.w};
#pragma unroll
    for (int r = 0; r < 4; ++r)
#pragma unroll
      for (int j = 0; j < 4; ++j) {
        acc[r][j] = fmaf(qv[r], sv[j], acc[r][j]);
        sc[r][j] = fmaf(qv[r], vv[j], sc[r][j]);
      }
  }
  __syncthreads();
#pragma unroll
  for (int r = 0; r < 4; ++r)
#pragma unroll
    for (int m = 0; m < 4; ++m) {
      int ll = lg * 4 + r, tt = eg * 4 + m;
      SW[ll][tt] = (tt <= ll) ? sc[r][m] * gl[tt] : 0.f;
    }
  __syncthreads();
  for (int t = 0; t < 64; ++t) {
    float wv4[4], kv4[4];
#pragma unroll
    for (int r = 0; r < 4; ++r) wv4[r] = SW[lg * 4 + r][t];
#pragma unroll
    for (int j = 0; j < 4; ++j) kv4[j] = kb[eg * 4 + j][t];
#pragma unroll
    for (int r = 0; r < 4; ++r)
#pragma unroll
      for (int j = 0; j < 4; ++j)
        acc[r][j] = fmaf(wv4[r], kv4[j], acc[r][j]);
  }
  float val[4][4];
  int egw = (tid >> 4) & 3;
#pragma unroll
  for (int r = 0; r < 4; ++r) {
    float gi = 1.f / Gs[lg * 4 + r];
    float pr = 0.f;
#pragma unroll
    for (int j = 0; j < 4; ++j) { float v = acc[r][j] * gi; val[r][j] = v; pr = fmaf(v, v, pr); }
    pr += __shfl_xor(pr, 16, 64);
    pr += __shfl_xor(pr, 32, 64);
    if (egw == 0) atomicAdd(&rsq[lg * 4 + r], pr);
  }
  __syncthreads();
#pragma unroll
  for (int r = 0; r < 4; ++r) {
    float inv = 1.f / fmaxf(sqrtf(rsq[lg * 4 + r]), EPSF);
    union { ushort4 u; __hip_bfloat16 hh[4]; } pk;
#pragma unroll
    for (int j = 0; j < 4; ++j) pk.hh[j] = __float2bfloat16(val[r][j] * inv);
    *(ushort4*)(sp + (size_t)(t0 + lg * 4 + r) * D_MODEL + h * 64 + eg * 4) = pk.u;
  }
}

// ---------------- final GEMM: out = sp @ wo^T + b (LDS-staged, same pipeline as gemm4) ----------------
__global__ __launch_bounds__(256) void gemm_out_kernel(const __hip_bfloat16* __restrict__ A,
    const __hip_bfloat16* __restrict__ W, const float* __restrict__ bias,
    float* __restrict__ O)
{
  __shared__ __align__(16) short lds_s[2][2][64 * GST];
  const int N = D_MODEL, K = D_MODEL;
  int tid = threadIdx.x;
  int lane = tid & 63;
  int wave = tid >> 6;
  int m_base = blockIdx.x * 64;
  int n_base = blockIdx.y * 64;
  int m0 = m_base + wave * 16;
  int n0 = n_base;
  int lrow = lane & 15, quad = lane >> 4;

  int r0 = tid >> 3, o0 = (tid & 7) * 8;
  int r1 = (tid + 256) >> 3, o1 = (tid & 7) * 8;
  const short* Ag0 = (const short*)A + (size_t)(m_base + r0) * K + o0;
  const short* Ag1 = (const short*)A + (size_t)(m_base + r1) * K + o1;
  const short* Wg0 = (const short*)W + (size_t)(n_base + r0) * K + o0;
  const short* Wg1 = (const short*)W + (size_t)(n_base + r1) * K + o1;
  int la0 = r0 * GST + o0;
  int la1 = r1 * GST + o1;

  f32x4 acc[4] = {};
  short8 ra0 = *(const short8*)(Ag0);
  short8 ra1 = *(const short8*)(Ag1);
  short8 rw0 = *(const short8*)(Wg0);
  short8 rw1 = *(const short8*)(Wg1);
#pragma unroll
  for (int t = 0; t < 8; ++t) {
    const int buf = t & 1;
    *(short8*)(&lds_s[buf][0][la0]) = ra0;
    *(short8*)(&lds_s[buf][0][la1]) = ra1;
    *(short8*)(&lds_s[buf][1][la0]) = rw0;
    *(short8*)(&lds_s[buf][1][la1]) = rw1;
    __syncthreads();
    if (t < 7) {
      ra0 = *(const short8*)(Ag0 + (t + 1) * 64);
      ra1 = *(const short8*)(Ag1 + (t + 1) * 64);
      rw0 = *(const short8*)(Wg0 + (t + 1) * 64);
      rw1 = *(const short8*)(Wg1 + (t + 1) * 64);
    }
    const short* As = lds_s[buf][0];
    const short* Ws = lds_s[buf][1];
#pragma unroll
    for (int kk = 0; kk < 2; ++kk) {
      short8 a = *(const short8*)(As + (wave * 16 + lrow) * GST + kk * 32 + quad * 8);
#pragma unroll
      for (int j = 0; j < 4; ++j) {
        short8 b = *(const short8*)(Ws + (j * 16 + lrow) * GST + kk * 32 + quad * 8);
        acc[j] = __builtin_amdgcn_mfma_f32_16x16x32_bf16(a, b, acc[j], 0, 0, 0);
      }
    }
  }
#pragma unroll
  for (int j = 0; j < 4; ++j) {
    int n = n0 + j * 16 + lrow;
    float bv = bias[n];
#pragma unroll
    for (int r = 0; r < 4; ++r)
      O[(size_t)(m0 + quad * 4 + r) * N + n] = acc[j][r] + bv;
  }
}

extern "C" void kernel_launch(void* const* d_in, const int* in_sizes, int n_in,
                              void* d_out, int out_size, void* d_ws, size_t ws_size,
                              hipStream_t stream) {
  const float* x = (const float*)d_in[0];
  const float* sb = (const float*)d_in[1];
  const float* wq_w = (const float*)d_in[2];
  const float* wq_b = (const float*)d_in[3];
  const float* wk_w = (const float*)d_in[4];
  const float* wk_b = (const float*)d_in[5];
  const float* wv_w = (const float*)d_in[6];
  const float* wv_b = (const float*)d_in[7];
  const float* wo_w = (const float*)d_in[8];
  const float* wo_b = (const float*)d_in[9];
  const float* td_w = (const float*)d_in[10];
  const float* td_b = (const float*)d_in[11];
  const float* wgz_w = (const float*)d_in[12];
  const float* wgz_b = (const float*)d_in[13];
  const float* kvs = (const float*)d_in[14];
  float* out = (float*)d_out;

  char* ws = (char*)d_ws;
  size_t off = 0;
  auto alloc = [&](size_t bytes) -> void* {
    void* p = ws + off;
    off += (bytes + 255) & ~(size_t)255;
    return p;
  };
  __hip_bfloat16* xb  = (__hip_bfloat16*)alloc((size_t)L_SEQ * D_MODEL * 2);
  __hip_bfloat16* sbb = (__hip_bfloat16*)alloc((size_t)L_SEQ * D_MODEL * 2);
  __hip_bfloat16* wqb = (__hip_bfloat16*)alloc((size_t)D_MODEL * D_MODEL * 2);
  __hip_bfloat16* wkb = (__hip_bfloat16*)alloc((size_t)D_MODEL * D_MODEL * 2);
  __hip_bfloat16* wvb = (__hip_bfloat16*)alloc((size_t)D_MODEL * D_MODEL * 2);
  __hip_bfloat16* tdb = (__hip_bfloat16*)alloc((size_t)D_MODEL * D_MODEL * 2);
  __hip_bfloat16* wob = (__hip_bfloat16*)alloc((size_t)D_MODEL * D_MODEL * 2);
  __hip_bfloat16* spb = (__hip_bfloat16*)alloc((size_t)L_SEQ * D_MODEL * 2);
  _Float16* ku16 = (_Float16*)alloc((size_t)D_MODEL * UPAD * 2);
  _Float16* vu16 = (_Float16*)alloc((size_t)D_MODEL * UPAD * 2);
  float* qbuf  = (float*)alloc((size_t)L_SEQ * D_MODEL * 4);
  float* fT    = (float*)alloc((size_t)D_MODEL * L_SEQ * 4);
  float* kfT   = (float*)alloc((size_t)D_MODEL * L_SEQ * 4);
  float* vfT   = (float*)alloc((size_t)D_MODEL * L_SEQ * 4);
  float* gbuf  = (float*)alloc((size_t)NH * L_SEQ * 4);
  float* gsum  = (float*)alloc((size_t)NH * 32 * 4);
  float* Abuf  = (float*)alloc((size_t)NH * 32 * 4096 * 4);

  prep_kernel<<<13568, 256, 0, stream>>>(x, sb, wq_w, wk_w, wv_w, td_w, wo_w,
                                         xb, sbb, wqb, wkb, wvb, tdb, wob,
                                         ku16, vu16);
  gemm4_kernel<<<dim3(L_SEQ / 64, D_MODEL / 64, 4), 256, 0, stream>>>(
      xb, sbb, wqb, wkb, wvb, tdb, wq_b, wk_b, wv_b, td_b, qbuf, fT,
      ku16, vu16);
  conv_kernel<<<512, 256, 0, stream>>>(ku16, vu16, fT, kfT, vfT);
  gatepart_kernel<<<dim3(32, 8), 256, 0, stream>>>(kfT, vfT, wgz_w, wgz_b, kvs, gbuf, Abuf, gsum);
  prefix_kernel<<<128, 256, 0, stream>>>(Abuf, gsum);
  attn_kernel<<<dim3(32, 8), 256, 0, stream>>>(qbuf, kfT, vfT, gbuf, Abuf, gsum, spb);
  gemm_out_kernel<<<dim3(L_SEQ / 64, D_MODEL / 64), 256, 0, stream>>>(spb, wob, wo_b, out);
}

// Round 7
// 153.847 us; speedup vs baseline: 1.5218x; 1.0182x over previous
//
#include <hip/hip_runtime.h>
#include <hip/hip_bf16.h>
#include <hip/hip_fp16.h>

#define L_SEQ 2048
#define D_MODEL 512
#define NH 8
#define HD 64
#define EPSF 1e-5f

// u f16 layout: [512 ch][2560], logical s at col 256+s; margins zeroed.
#define UPAD 2560
#define UOFF 256
// filter LDS: 8 phase copies, stride 2120 f16 (=1060 words, == 4 mod 32 -> 2-way-free banks)
#define XLEN 2112
#define XPAD 2120

// staged-GEMM LDS: row stride 72 shorts (144B) -> per-b128-wave-read exactly 8 words/bank
#define GST 72

typedef __attribute__((ext_vector_type(8))) short short8;
typedef __attribute__((ext_vector_type(8))) _Float16 half8;
typedef __attribute__((ext_vector_type(4))) _Float16 half4v;
typedef __attribute__((ext_vector_type(4))) float f32x4;

// load 8 consecutive fp32, convert to bf16 short8 (same __float2bfloat16 rounding)
__device__ inline short8 cvt8v(const float* __restrict__ p) {
  float4 f0 = *(const float4*)p;
  float4 f1 = *(const float4*)(p + 4);
  short8 r;
  union { __hip_bfloat16 h; short s; } u;
  u.h = __float2bfloat16(f0.x); r[0] = u.s;
  u.h = __float2bfloat16(f0.y); r[1] = u.s;
  u.h = __float2bfloat16(f0.z); r[2] = u.s;
  u.h = __float2bfloat16(f0.w); r[3] = u.s;
  u.h = __float2bfloat16(f1.x); r[4] = u.s;
  u.h = __float2bfloat16(f1.y); r[5] = u.s;
  u.h = __float2bfloat16(f1.z); r[6] = u.s;
  u.h = __float2bfloat16(f1.w); r[7] = u.s;
  return r;
}

// ---------------- prep: fp32->bf16 for 7 tensors (8 elems/thread) + zero u16 margins ----------------
__global__ __launch_bounds__(256) void prep_kernel(const float* __restrict__ x,
    const float* __restrict__ sb, const float* __restrict__ wq, const float* __restrict__ wk,
    const float* __restrict__ wv, const float* __restrict__ td, const float* __restrict__ wo,
    __hip_bfloat16* __restrict__ xb, __hip_bfloat16* __restrict__ sbb,
    __hip_bfloat16* __restrict__ wqb, __hip_bfloat16* __restrict__ wkb,
    __hip_bfloat16* __restrict__ wvb, __hip_bfloat16* __restrict__ tdb,
    __hip_bfloat16* __restrict__ wob,
    _Float16* __restrict__ ku16, _Float16* __restrict__ vu16)
{
  int i = blockIdx.x * 256 + threadIdx.x;
  if (i < 425984) {  // 3407872 elems / 8
    size_t base = (size_t)i * 8;
    const float* s;
    __hip_bfloat16* d;
    size_t r;
    if (base < 1048576) { s = x; d = xb; r = base; }
    else if (base < 2097152) { s = sb; d = sbb; r = base - 1048576; }
    else {
      size_t j = base - 2097152;
      int w = (int)(j >> 18);
      r = j & 262143;
      s = (w == 0) ? wq : (w == 1) ? wk : (w == 2) ? wv : (w == 3) ? td : wo;
      d = (w == 0) ? wqb : (w == 1) ? wkb : (w == 2) ? wvb : (w == 3) ? tdb : wob;
    }
    *(short8*)((short*)d + r) = cvt8v(s + r);
  } else if (i < 491520) {
    // zero u16 margins: 2 arrays x 512 rows x 64 chunks of 8 f16 (16B)
    int t = i - 425984;
    int arr = t >> 15;
    int rem = t & 32767;
    int row = rem >> 6;
    int cc = rem & 63;
    int col = (cc < 32) ? cc * 8 : 2304 + (cc - 32) * 8;
    _Float16* base = arr ? vu16 : ku16;
    *(int4*)(base + (size_t)row * UPAD + col) = int4{0, 0, 0, 0};
  }
}

// ---------------- batched GEMM: q,k,v,filters; LDS-staged 2-phase pipeline ----------------
__global__ __launch_bounds__(256) void gemm4_kernel(
    const __hip_bfloat16* __restrict__ xb, const __hip_bfloat16* __restrict__ sbb,
    const __hip_bfloat16* __restrict__ wqb, const __hip_bfloat16* __restrict__ wkb,
    const __hip_bfloat16* __restrict__ wvb, const __hip_bfloat16* __restrict__ tdb,
    const float* __restrict__ bq, const float* __restrict__ bk,
    const float* __restrict__ bv, const float* __restrict__ btd,
    float* __restrict__ qout, float* __restrict__ fT,
    _Float16* __restrict__ ku16, _Float16* __restrict__ vu16)
{
  __shared__ __align__(16) short lds_s[2][2][64 * GST];
  int z = blockIdx.z;
  const __hip_bfloat16* A = (z == 3) ? sbb : xb;
  const __hip_bfloat16* W = (z == 0) ? wqb : (z == 1) ? wkb : (z == 2) ? wvb : tdb;
  const float* bias = (z == 0) ? bq : (z == 1) ? bk : (z == 2) ? bv : btd;
  const int M = L_SEQ, N = D_MODEL, K = D_MODEL;
  int tid = threadIdx.x;
  int lane = tid & 63;
  int wave = tid >> 6;
  int m_base = blockIdx.x * 64;
  int n_base = blockIdx.y * 64;
  int m0 = m_base + wave * 16;
  int n0 = n_base;
  int lrow = lane & 15, quad = lane >> 4;

  int r0 = tid >> 3, o0 = (tid & 7) * 8;
  int r1 = (tid + 256) >> 3, o1 = (tid & 7) * 8;
  const short* Ag0 = (const short*)A + (size_t)(m_base + r0) * K + o0;
  const short* Ag1 = (const short*)A + (size_t)(m_base + r1) * K + o1;
  const short* Wg0 = (const short*)W + (size_t)(n_base + r0) * K + o0;
  const short* Wg1 = (const short*)W + (size_t)(n_base + r1) * K + o1;
  int la0 = r0 * GST + o0;
  int la1 = r1 * GST + o1;

  f32x4 acc[4] = {};
  short8 ra0 = *(const short8*)(Ag0);
  short8 ra1 = *(const short8*)(Ag1);
  short8 rw0 = *(const short8*)(Wg0);
  short8 rw1 = *(const short8*)(Wg1);
#pragma unroll
  for (int t = 0; t < 8; ++t) {
    const int buf = t & 1;
    *(short8*)(&lds_s[buf][0][la0]) = ra0;
    *(short8*)(&lds_s[buf][0][la1]) = ra1;
    *(short8*)(&lds_s[buf][1][la0]) = rw0;
    *(short8*)(&lds_s[buf][1][la1]) = rw1;
    __syncthreads();
    if (t < 7) {
      ra0 = *(const short8*)(Ag0 + (t + 1) * 64);
      ra1 = *(const short8*)(Ag1 + (t + 1) * 64);
      rw0 = *(const short8*)(Wg0 + (t + 1) * 64);
      rw1 = *(const short8*)(Wg1 + (t + 1) * 64);
    }
    const short* As = lds_s[buf][0];
    const short* Ws = lds_s[buf][1];
#pragma unroll
    for (int kk = 0; kk < 2; ++kk) {
      short8 a = *(const short8*)(As + (wave * 16 + lrow) * GST + kk * 32 + quad * 8);
#pragma unroll
      for (int j = 0; j < 4; ++j) {
        short8 b = *(const short8*)(Ws + (j * 16 + lrow) * GST + kk * 32 + quad * 8);
        acc[j] = __builtin_amdgcn_mfma_f32_16x16x32_bf16(a, b, acc[j], 0, 0, 0);
      }
    }
  }
  float bw[4];
#pragma unroll
  for (int j = 0; j < 4; ++j) bw[j] = bias[n0 + j * 16 + lrow];
  if (z == 0) {
#pragma unroll
    for (int j = 0; j < 4; ++j)
#pragma unroll
      for (int r = 0; r < 4; ++r)
        qout[(size_t)(m0 + quad * 4 + r) * N + n0 + j * 16 + lrow] = acc[j][r] + bw[j];
  } else if (z == 3) {
#pragma unroll
    for (int j = 0; j < 4; ++j) {
      float4 ov = {acc[j][0] + bw[j], acc[j][1] + bw[j], acc[j][2] + bw[j], acc[j][3] + bw[j]};
      *(float4*)(fT + (size_t)(n0 + j * 16 + lrow) * M + m0 + quad * 4) = ov;
    }
  } else {
    float val[4][4];
#pragma unroll
    for (int j = 0; j < 4; ++j)
#pragma unroll
      for (int r = 0; r < 4; ++r) val[j][r] = acc[j][r] + bw[j];
    float pr[4];
#pragma unroll
    for (int r = 0; r < 4; ++r)
      pr[r] = val[0][r] * val[0][r] + val[1][r] * val[1][r] +
              val[2][r] * val[2][r] + val[3][r] * val[3][r];
#pragma unroll
    for (int off = 1; off < 16; off <<= 1)
#pragma unroll
      for (int r = 0; r < 4; ++r)
        pr[r] += __shfl_xor(pr[r], off, 64);
    _Float16* u16 = (z == 1) ? ku16 : vu16;
#pragma unroll
    for (int r = 0; r < 4; ++r) {
      float inv = 1.f / fmaxf(sqrtf(pr[r]), EPSF);
#pragma unroll
      for (int j = 0; j < 4; ++j) val[j][r] *= inv;
    }
#pragma unroll
    for (int j = 0; j < 4; ++j) {
      half4v pk = {(_Float16)val[j][0], (_Float16)val[j][1],
                   (_Float16)val[j][2], (_Float16)val[j][3]};
      *(half4v*)(u16 + (size_t)(n0 + j * 16 + lrow) * UPAD + UOFF + m0 + quad * 4) = pk;
    }
  }
}

// ---------------- causal conv via MFMA Toeplitz, filter in LDS (f16) ----------------
// Staging vectorized: filter read ONCE as float4 (2 loads/thread, was 72 scalar),
// fanned out to the 8 phase copies; exact-cover margin zeroing.
// lds_f[p][x] = f16(F[2063-x-p]); valid j in [0,2048) covers x in [16-p, 2063-p];
// margins x in [0,16-p) u [2064-p, 2112) zeroed (union = [0,2112) exactly).
__global__ __launch_bounds__(256) void conv_kernel(
    const _Float16* __restrict__ ku16, const _Float16* __restrict__ vu16,
    const float* __restrict__ fT, float* __restrict__ oK, float* __restrict__ oV)
{
  __shared__ _Float16 lds_f[8 * XPAD];
  int c = blockIdx.x;
  int tid = threadIdx.x;
  const float* Fc = fT + (size_t)c * L_SEQ;
#pragma unroll
  for (int s = 0; s < 2; ++s) {
    int idx = tid + s * 256;           // 0..511 = 8 phases x 64 margin slots
    int p = idx >> 6, m = idx & 63;
    int xx = (m < 16 - p) ? m : 2048 + m;
    lds_f[p * XPAD + xx] = (_Float16)0.f;
  }
#pragma unroll
  for (int it = 0; it < 2; ++it) {
    int j0 = it * 1024 + tid * 4;
    float4 f = *(const float4*)(Fc + j0);
    _Float16 h4[4] = {(_Float16)f.x, (_Float16)f.y, (_Float16)f.z, (_Float16)f.w};
#pragma unroll
    for (int e = 0; e < 4; ++e) {
      int xbase = 2063 - (j0 + e);
#pragma unroll
      for (int p = 0; p < 8; ++p)
        lds_f[p * XPAD + (xbase - p)] = h4[e];
    }
  }
  __syncthreads();

  int wave = tid >> 6, lane = tid & 63;
  int pair = wave;
  int l0_lo = 256 * pair;
  int l0_hi = 1792 - l0_lo;
  int mn = lane & 15, quad = lane >> 4;

  const _Float16* puk = ku16 + (size_t)c * UPAD + 16 * mn + 8 * quad;
  const _Float16* puv = vu16 + (size_t)c * UPAD + 16 * mn + 8 * quad;

  int j0c = 2063 - mn;
  int p8 = j0c & 7;
  int xb0 = (j0c - p8) + 8 * quad;
  const _Float16* pf_hi = lds_f + p8 * XPAD + (xb0 - (l0_hi + 256));
  const _Float16* pf_lo = lds_f + p8 * XPAD + (xb0 - (l0_lo + 256));

  int steps_lo = pair * 8 + 9;
  int steps_hi = 65 - pair * 8;
  f32x4 ak_hi = {}, ak_lo = {}, av_hi = {}, av_lo = {};
  half8 bk = *(const half8*)puk;
  half8 bv = *(const half8*)puv;
  half8 fh = *(const half8*)pf_hi;
  half8 fl = *(const half8*)pf_lo;
#pragma unroll 2
  for (int i = 0; i < steps_lo; ++i) {
    puk += 32; puv += 32; pf_hi += 32; pf_lo += 32;
    half8 bk_n = *(const half8*)puk;
    half8 bv_n = *(const half8*)puv;
    half8 fh_n = *(const half8*)pf_hi;
    half8 fl_n = *(const half8*)pf_lo;
    ak_hi = __builtin_amdgcn_mfma_f32_16x16x32_f16(fh, bk, ak_hi, 0, 0, 0);
    av_hi = __builtin_amdgcn_mfma_f32_16x16x32_f16(fh, bv, av_hi, 0, 0, 0);
    ak_lo = __builtin_amdgcn_mfma_f32_16x16x32_f16(fl, bk, ak_lo, 0, 0, 0);
    av_lo = __builtin_amdgcn_mfma_f32_16x16x32_f16(fl, bv, av_lo, 0, 0, 0);
    bk = bk_n; bv = bv_n; fh = fh_n; fl = fl_n;
  }
#pragma unroll 2
  for (int i = steps_lo; i < steps_hi; ++i) {
    puk += 32; puv += 32; pf_hi += 32;
    half8 bk_n = *(const half8*)puk;
    half8 bv_n = *(const half8*)puv;
    half8 fh_n = *(const half8*)pf_hi;
    ak_hi = __builtin_amdgcn_mfma_f32_16x16x32_f16(fh, bk, ak_hi, 0, 0, 0);
    av_hi = __builtin_amdgcn_mfma_f32_16x16x32_f16(fh, bv, av_hi, 0, 0, 0);
    bk = bk_n; bv = bv_n; fh = fh_n;
  }
  size_t ob = (size_t)c * L_SEQ + 16 * mn + 4 * quad;
  *(float4*)(oK + ob + l0_hi) = float4{ak_hi[0], ak_hi[1], ak_hi[2], ak_hi[3]};
  *(float4*)(oK + ob + l0_lo) = float4{ak_lo[0], ak_lo[1], ak_lo[2], ak_lo[3]};
  *(float4*)(oV + ob + l0_hi) = float4{av_hi[0], av_hi[1], av_hi[2], av_hi[3]};
  *(float4*)(oV + ob + l0_lo) = float4{av_lo[0], av_lo[1], av_lo[2], av_lo[3]};
}

// ---------------- fused gate + partials per (h, chunk); float4-staged ----------------
__global__ __launch_bounds__(256) void gatepart_kernel(const float* __restrict__ kf,
    const float* __restrict__ vf, const float* __restrict__ wgz_w,
    const float* __restrict__ wgz_b, const float* __restrict__ kvs,
    float* __restrict__ g, float* __restrict__ A, float* __restrict__ gsum)
{
  __shared__ float MT[64][68];
  __shared__ float kb[64][68];
  __shared__ float kbT[64][68];
  __shared__ float vb[64][68];
  __shared__ float yb[64][68];
  __shared__ float part[4][64];
  __shared__ float gl[64];
  int h = blockIdx.y, ch = blockIdx.x;
  int t0 = ch * 64, tid = threadIdx.x;
#pragma unroll
  for (int k = 0; k < 4; ++k) {
    int e = tid + k * 256;            // 0..1023
    int a = e >> 4, b4 = (e & 15) * 4;
    float4 wv = *(const float4*)(wgz_w + a * 64 + b4);
    float4 sv = *(const float4*)(kvs + a * 64 + b4);
    MT[b4 + 0][a] = wv.x * sv.x;
    MT[b4 + 1][a] = wv.y * sv.y;
    MT[b4 + 2][a] = wv.z * sv.z;
    MT[b4 + 3][a] = wv.w * sv.w;
    float4 kv = *(const float4*)(kf + (size_t)(h * 64 + a) * L_SEQ + t0 + b4);
    *(float4*)(&kb[a][b4]) = kv;
    kbT[b4 + 0][a] = kv.x;
    kbT[b4 + 1][a] = kv.y;
    kbT[b4 + 2][a] = kv.z;
    kbT[b4 + 3][a] = kv.w;
    float4 vv = *(const float4*)(vf + (size_t)(h * 64 + a) * L_SEQ + t0 + b4);
    *(float4*)(&vb[a][b4]) = vv;
  }
  __syncthreads();
  int lg = tid & 15, dg = tid >> 4;
  {
    float acc[4][4] = {};
    for (int e = 0; e < 64; ++e) {
      float4 mv4 = *(const float4*)(&MT[e][dg * 4]);
      float4 kv4 = *(const float4*)(&kb[e][lg * 4]);
      float mvv[4] = {mv4.x, mv4.y, mv4.z, mv4.w};
      float kvv[4] = {kv4.x, kv4.y, kv4.z, kv4.w};
#pragma unroll
      for (int r = 0; r < 4; ++r)
#pragma unroll
        for (int j = 0; j < 4; ++j)
          acc[r][j] = fmaf(mvv[r], kvv[j], acc[r][j]);
    }
#pragma unroll
    for (int r = 0; r < 4; ++r)
#pragma unroll
      for (int j = 0; j < 4; ++j)
        yb[dg * 4 + r][lg * 4 + j] = acc[r][j];
  }
  __syncthreads();
  {
    int l = tid & 63, p = tid >> 6;
    float s = 0.f;
#pragma unroll
    for (int dd = 0; dd < 16; ++dd)
      s = fmaf(yb[p * 16 + dd][l], vb[p * 16 + dd][l], s);
    part[p][l] = s;
  }
  __syncthreads();
  if (tid < 64) {
    float logit = part[0][tid] + part[1][tid] + part[2][tid] + part[3][tid] + wgz_b[0];
    float rl = fmaxf(logit, 0.f);
    float gv = rl * rl + EPSF;
    g[h * L_SEQ + t0 + tid] = gv;
    gl[tid] = gv;
  }
  __syncthreads();
  if (tid < 64) {
    float s = gl[tid];
#pragma unroll
    for (int off = 1; off < 64; off <<= 1) s += __shfl_xor(s, off, 64);
    if (tid == 0) gsum[h * 32 + ch] = s;
  }
  int eg = tid & 15, dg2 = tid >> 4;
  float acc[4][4] = {};
  for (int t = 0; t < 64; ++t) {
    float gt = gl[t];
    float4 k4 = *(const float4*)(&kbT[t][eg * 4]);
    float kv4[4] = {k4.x * gt, k4.y * gt, k4.z * gt, k4.w * gt};
    float vv4[4];
#pragma unroll
    for (int r = 0; r < 4; ++r) vv4[r] = vb[dg2 * 4 + r][t];
#pragma unroll
    for (int r = 0; r < 4; ++r)
#pragma unroll
      for (int j = 0; j < 4; ++j)
        acc[r][j] = fmaf(vv4[r], kv4[j], acc[r][j]);
  }
  float* Ap = A + ((size_t)(h * 32 + ch)) * 4096;
#pragma unroll
  for (int r = 0; r < 4; ++r)
#pragma unroll
    for (int j = 0; j < 4; ++j)
      Ap[(dg2 * 4 + r) * 64 + eg * 4 + j] = acc[r][j];
}

// ---------------- exclusive prefix over 32 chunks (in place), ILP version ----------------
__global__ void prefix_kernel(float* __restrict__ A, float* __restrict__ gsum)
{
  int flat = blockIdx.x * 256 + threadIdx.x;
  int h = flat >> 12, de = flat & 4095;
  size_t base = (size_t)h * 32 * 4096 + de;
  float v[32];
#pragma unroll
  for (int c = 0; c < 32; ++c) v[c] = A[base + (size_t)c * 4096];
  float run = 0.f;
#pragma unroll
  for (int c = 0; c < 32; ++c) {
    A[base + (size_t)c * 4096] = run;
    run += v[c];
  }
  if (flat < 8) {
    float t[32];
#pragma unroll
    for (int c = 0; c < 32; ++c) t[c] = gsum[flat * 32 + c];
    float r = 0.f;
#pragma unroll
    for (int c = 0; c < 32; ++c) { gsum[flat * 32 + c] = r; r += t[c]; }
  }
}

// ---------------- attention: carry + in-chunk gated quadratic; float4-staged ----------------
__global__ __launch_bounds__(256) void attn_kernel(const float* __restrict__ q,
    const float* __restrict__ kf, const float* __restrict__ vf, const float* __restrict__ g,
    const float* __restrict__ Sprev, const float* __restrict__ Gprev,
    __hip_bfloat16* __restrict__ sp)
{
  __shared__ float qT[64][68];
  __shared__ float SW[64][69];
  __shared__ float vb[64][68];
  __shared__ float kb[64][69];
  __shared__ float gl[64], Gs[64], rsq[64];
  int h = blockIdx.y, ch = blockIdx.x;
  int t0 = ch * 64, tid = threadIdx.x;
  const float* Sp = Sprev + ((size_t)(h * 32 + ch)) * 4096;
#pragma unroll
  for (int k = 0; k < 4; ++k) {
    int e = tid + k * 256;
    int a = e >> 4, b4 = (e & 15) * 4;
    float4 qv = *(const float4*)(q + (size_t)(t0 + a) * D_MODEL + h * 64 + b4);
    qT[b4 + 0][a] = qv.x;
    qT[b4 + 1][a] = qv.y;
    qT[b4 + 2][a] = qv.z;
    qT[b4 + 3][a] = qv.w;
    float4 sv = *(const float4*)(Sp + a * 64 + b4);
    SW[a][b4 + 0] = sv.x;
    SW[a][b4 + 1] = sv.y;
    SW[a][b4 + 2] = sv.z;
    SW[a][b4 + 3] = sv.w;
    float4 vv = *(const float4*)(vf + (size_t)(h * 64 + a) * L_SEQ + t0 + b4);
    *(float4*)(&vb[a][b4]) = vv;
    float4 kv = *(const float4*)(kf + (size_t)(h * 64 + a) * L_SEQ + t0 + b4);
    kb[a][b4 + 0] = kv.x;
    kb[a][b4 + 1] = kv.y;
    kb[a][b4 + 2] = kv.z;
    kb[a][b4 + 3] = kv.w;
  }
  if (tid < 64) { gl[tid] = g[h * L_SEQ + t0 + tid]; rsq[tid] = 0.f; }
  __syncthreads();
  if (tid < 64) {
    float val = gl[tid];
#pragma unroll
    for (int off = 1; off < 64; off <<= 1) {
      float o = __shfl_up(val, (unsigned)off, 64);
      if (tid >= off) val += o;
    }
    Gs[tid] = fmaxf(Gprev[h * 32 + ch] + val, EPSF);
  }
  int lg = tid & 15, eg = tid >> 4;
  float acc[4][4] = {};
  float sc[4][4] = {};
  for (int d = 0; d < 64; ++d) {
    float4 q4 = *(const float4*)(&qT[d][lg * 4]);
    float qv[4] = {q4.x, q4.y, q4.z, q4.w};
    float sv[4];
#pragma unroll
    for (int j = 0; j < 4; ++j) sv[j] = SW[d][eg * 4 + j];
    float4 v4 = *(const float4*)(&vb[d][eg * 4]);
    float vv[4] = {v4.x, v4.y, v4.z, v4.w};
#pragma unroll
    for (int r = 0; r < 4; ++r)
#pragma unroll
      for (int j = 0; j < 4; ++j) {
        acc[r][j] = fmaf(qv[r], sv[j], acc[r][j]);
        sc[r][j] = fmaf(qv[r], vv[j], sc[r][j]);
      }
  }
  __syncthreads();
#pragma unroll
  for (int r = 0; r < 4; ++r)
#pragma unroll
    for (int m = 0; m < 4; ++m) {
      int ll = lg * 4 + r, tt = eg * 4 + m;
      SW[ll][tt] = (tt <= ll) ? sc[r][m] * gl[tt] : 0.f;
    }
  __syncthreads();
  for (int t = 0; t < 64; ++t) {
    float wv4[4], kv4[4];
#pragma unroll
    for (int r = 0; r < 4; ++r) wv4[r] = SW[lg * 4 + r][t];
#pragma unroll
    for (int j = 0; j < 4; ++j) kv4[j] = kb[eg * 4 + j][t];
#pragma unroll
    for (int r = 0; r < 4; ++r)
#pragma unroll
      for (int j = 0; j < 4; ++j)
        acc[r][j] = fmaf(wv4[r], kv4[j], acc[r][j]);
  }
  float val[4][4];
  int egw = (tid >> 4) & 3;
#pragma unroll
  for (int r = 0; r < 4; ++r) {
    float gi = 1.f / Gs[lg * 4 + r];
    float pr = 0.f;
#pragma unroll
    for (int j = 0; j < 4; ++j) { float v = acc[r][j] * gi; val[r][j] = v; pr = fmaf(v, v, pr); }
    pr += __shfl_xor(pr, 16, 64);
    pr += __shfl_xor(pr, 32, 64);
    if (egw == 0) atomicAdd(&rsq[lg * 4 + r], pr);
  }
  __syncthreads();
#pragma unroll
  for (int r = 0; r < 4; ++r) {
    float inv = 1.f / fmaxf(sqrtf(rsq[lg * 4 + r]), EPSF);
    union { ushort4 u; __hip_bfloat16 hh[4]; } pk;
#pragma unroll
    for (int j = 0; j < 4; ++j) pk.hh[j] = __float2bfloat16(val[r][j] * inv);
    *(ushort4*)(sp + (size_t)(t0 + lg * 4 + r) * D_MODEL + h * 64 + eg * 4) = pk.u;
  }
}

// ---------------- final GEMM: out = sp @ wo^T + b (LDS-staged, same pipeline as gemm4) ----------------
__global__ __launch_bounds__(256) void gemm_out_kernel(const __hip_bfloat16* __restrict__ A,
    const __hip_bfloat16* __restrict__ W, const float* __restrict__ bias,
    float* __restrict__ O)
{
  __shared__ __align__(16) short lds_s[2][2][64 * GST];
  const int N = D_MODEL, K = D_MODEL;
  int tid = threadIdx.x;
  int lane = tid & 63;
  int wave = tid >> 6;
  int m_base = blockIdx.x * 64;
  int n_base = blockIdx.y * 64;
  int m0 = m_base + wave * 16;
  int n0 = n_base;
  int lrow = lane & 15, quad = lane >> 4;

  int r0 = tid >> 3, o0 = (tid & 7) * 8;
  int r1 = (tid + 256) >> 3, o1 = (tid & 7) * 8;
  const short* Ag0 = (const short*)A + (size_t)(m_base + r0) * K + o0;
  const short* Ag1 = (const short*)A + (size_t)(m_base + r1) * K + o1;
  const short* Wg0 = (const short*)W + (size_t)(n_base + r0) * K + o0;
  const short* Wg1 = (const short*)W + (size_t)(n_base + r1) * K + o1;
  int la0 = r0 * GST + o0;
  int la1 = r1 * GST + o1;

  f32x4 acc[4] = {};
  short8 ra0 = *(const short8*)(Ag0);
  short8 ra1 = *(const short8*)(Ag1);
  short8 rw0 = *(const short8*)(Wg0);
  short8 rw1 = *(const short8*)(Wg1);
#pragma unroll
  for (int t = 0; t < 8; ++t) {
    const int buf = t & 1;
    *(short8*)(&lds_s[buf][0][la0]) = ra0;
    *(short8*)(&lds_s[buf][0][la1]) = ra1;
    *(short8*)(&lds_s[buf][1][la0]) = rw0;
    *(short8*)(&lds_s[buf][1][la1]) = rw1;
    __syncthreads();
    if (t < 7) {
      ra0 = *(const short8*)(Ag0 + (t + 1) * 64);
      ra1 = *(const short8*)(Ag1 + (t + 1) * 64);
      rw0 = *(const short8*)(Wg0 + (t + 1) * 64);
      rw1 = *(const short8*)(Wg1 + (t + 1) * 64);
    }
    const short* As = lds_s[buf][0];
    const short* Ws = lds_s[buf][1];
#pragma unroll
    for (int kk = 0; kk < 2; ++kk) {
      short8 a = *(const short8*)(As + (wave * 16 + lrow) * GST + kk * 32 + quad * 8);
#pragma unroll
      for (int j = 0; j < 4; ++j) {
        short8 b = *(const short8*)(Ws + (j * 16 + lrow) * GST + kk * 32 + quad * 8);
        acc[j] = __builtin_amdgcn_mfma_f32_16x16x32_bf16(a, b, acc[j], 0, 0, 0);
      }
    }
  }
#pragma unroll
  for (int j = 0; j < 4; ++j) {
    int n = n0 + j * 16 + lrow;
    float bv = bias[n];
#pragma unroll
    for (int r = 0; r < 4; ++r)
      O[(size_t)(m0 + quad * 4 + r) * N + n] = acc[j][r] + bv;
  }
}

extern "C" void kernel_launch(void* const* d_in, const int* in_sizes, int n_in,
                              void* d_out, int out_size, void* d_ws, size_t ws_size,
                              hipStream_t stream) {
  const float* x = (const float*)d_in[0];
  const float* sb = (const float*)d_in[1];
  const float* wq_w = (const float*)d_in[2];
  const float* wq_b = (const float*)d_in[3];
  const float* wk_w = (const float*)d_in[4];
  const float* wk_b = (const float*)d_in[5];
  const float* wv_w = (const float*)d_in[6];
  const float* wv_b = (const float*)d_in[7];
  const float* wo_w = (const float*)d_in[8];
  const float* wo_b = (const float*)d_in[9];
  const float* td_w = (const float*)d_in[10];
  const float* td_b = (const float*)d_in[11];
  const float* wgz_w = (const float*)d_in[12];
  const float* wgz_b = (const float*)d_in[13];
  const float* kvs = (const float*)d_in[14];
  float* out = (float*)d_out;

  char* ws = (char*)d_ws;
  size_t off = 0;
  auto alloc = [&](size_t bytes) -> void* {
    void* p = ws + off;
    off += (bytes + 255) & ~(size_t)255;
    return p;
  };
  __hip_bfloat16* xb  = (__hip_bfloat16*)alloc((size_t)L_SEQ * D_MODEL * 2);
  __hip_bfloat16* sbb = (__hip_bfloat16*)alloc((size_t)L_SEQ * D_MODEL * 2);
  __hip_bfloat16* wqb = (__hip_bfloat16*)alloc((size_t)D_MODEL * D_MODEL * 2);
  __hip_bfloat16* wkb = (__hip_bfloat16*)alloc((size_t)D_MODEL * D_MODEL * 2);
  __hip_bfloat16* wvb = (__hip_bfloat16*)alloc((size_t)D_MODEL * D_MODEL * 2);
  __hip_bfloat16* tdb = (__hip_bfloat16*)alloc((size_t)D_MODEL * D_MODEL * 2);
  __hip_bfloat16* wob = (__hip_bfloat16*)alloc((size_t)D_MODEL * D_MODEL * 2);
  __hip_bfloat16* spb = (__hip_bfloat16*)alloc((size_t)L_SEQ * D_MODEL * 2);
  _Float16* ku16 = (_Float16*)alloc((size_t)D_MODEL * UPAD * 2);
  _Float16* vu16 = (_Float16*)alloc((size_t)D_MODEL * UPAD * 2);
  float* qbuf  = (float*)alloc((size_t)L_SEQ * D_MODEL * 4);
  float* fT    = (float*)alloc((size_t)D_MODEL * L_SEQ * 4);
  float* kfT   = (float*)alloc((size_t)D_MODEL * L_SEQ * 4);
  float* vfT   = (float*)alloc((size_t)D_MODEL * L_SEQ * 4);
  float* gbuf  = (float*)alloc((size_t)NH * L_SEQ * 4);
  float* gsum  = (float*)alloc((size_t)NH * 32 * 4);
  float* Abuf  = (float*)alloc((size_t)NH * 32 * 4096 * 4);

  prep_kernel<<<1920, 256, 0, stream>>>(x, sb, wq_w, wk_w, wv_w, td_w, wo_w,
                                        xb, sbb, wqb, wkb, wvb, tdb, wob,
                                        ku16, vu16);
  gemm4_kernel<<<dim3(L_SEQ / 64, D_MODEL / 64, 4), 256, 0, stream>>>(
      xb, sbb, wqb, wkb, wvb, tdb, wq_b, wk_b, wv_b, td_b, qbuf, fT,
      ku16, vu16);
  conv_kernel<<<512, 256, 0, stream>>>(ku16, vu16, fT, kfT, vfT);
  gatepart_kernel<<<dim3(32, 8), 256, 0, stream>>>(kfT, vfT, wgz_w, wgz_b, kvs, gbuf, Abuf, gsum);
  prefix_kernel<<<128, 256, 0, stream>>>(Abuf, gsum);
  attn_kernel<<<dim3(32, 8), 256, 0, stream>>>(qbuf, kfT, vfT, gbuf, Abuf, gsum, spb);
  gemm_out_kernel<<<dim3(L_SEQ / 64, D_MODEL / 64), 256, 0, stream>>>(spb, wob, wo_b, out);
}